// Round 1
// baseline (3200.102 us; speedup 1.0000x reference)
//
#include <hip/hip_runtime.h>
#include <math.h>

// ---- problem constants ----
#define Dm   512
#define Nn_  256
#define Bv   2
#define NBLK 6
#define BBAT 12            // NBLK*Bv
#define NT   3072          // BBAT*Nn_
#define NH   8
#define DH   64
#define DFF  1365
#define DFF2 2730
#define EPSR 1.1920929e-07f

// =====================================================================
// GEMM: C[i,j] = sum_k A[i*lda+k] * W[j*ldw+k] (+ bias[j])
// M must be a multiple of 64 (true for all call sites: 3072/6144/9216).
// =====================================================================
#define BM 64
#define BN 64
#define BKg 16

__global__ __launch_bounds__(256) void gemm_nt(
    const float* __restrict__ A, int lda,
    const float* __restrict__ W, int ldw,
    const float* __restrict__ bias,
    float* __restrict__ C, int ldc,
    int M, int Nd, int K)
{
    __shared__ float As[BKg][BM + 4];
    __shared__ float Bs[BKg][BN + 4];
    const int tid = threadIdx.x;
    const int i0 = blockIdx.x * BM;
    const int j0 = blockIdx.y * BN;
    const int tx = tid & 15;        // j-dir, 4 cols each
    const int ty = tid >> 4;        // i-dir, 4 rows each
    const int lk = tid & 15;        // k within tile for loads
    const int lrow = tid >> 4;      // row group for loads

    float acc[4][4] = {};

    for (int k0 = 0; k0 < K; k0 += BKg) {
        const int kk = k0 + lk;
        const bool kok = (kk < K);
        #pragma unroll
        for (int t = 0; t < 4; ++t) {
            const int i = lrow + t * 16;
            float va = 0.f, vb = 0.f;
            if (kok) {
                va = A[(size_t)(i0 + i) * lda + kk];
                if (j0 + i < Nd) vb = W[(size_t)(j0 + i) * ldw + kk];
            }
            As[lk][i] = va;
            Bs[lk][i] = vb;
        }
        __syncthreads();
        #pragma unroll
        for (int k = 0; k < BKg; ++k) {
            float a[4], b[4];
            #pragma unroll
            for (int c = 0; c < 4; ++c) a[c] = As[k][ty * 4 + c];
            #pragma unroll
            for (int c = 0; c < 4; ++c) b[c] = Bs[k][tx * 4 + c];
            #pragma unroll
            for (int ii = 0; ii < 4; ++ii)
                #pragma unroll
                for (int jj = 0; jj < 4; ++jj)
                    acc[ii][jj] = fmaf(a[ii], b[jj], acc[ii][jj]);
        }
        __syncthreads();
    }

    #pragma unroll
    for (int ii = 0; ii < 4; ++ii) {
        const int i = i0 + ty * 4 + ii;
        #pragma unroll
        for (int jj = 0; jj < 4; ++jj) {
            const int j = j0 + tx * 4 + jj;
            if (j < Nd) {
                float v = acc[ii][jj];
                if (bias) v += bias[j];
                C[(size_t)i * ldc + j] = v;
            }
        }
    }
}

static void launch_gemm(const float* A, int lda, const float* W, int ldw,
                        const float* bias, float* C, int ldc,
                        int M, int Nd, int K, hipStream_t stream)
{
    dim3 grid(M / BM, (Nd + BN - 1) / BN);
    gemm_nt<<<grid, 256, 0, stream>>>(A, lda, W, ldw, bias, C, ldc, M, Nd, K);
}

// =====================================================================
// RMSNorm: one block per row of 512
// =====================================================================
__global__ __launch_bounds__(256) void rmsnorm_kernel(
    const float* __restrict__ x, const float* __restrict__ w,
    float* __restrict__ y)
{
    const int r = blockIdx.x;
    const float* xr = x + (size_t)r * Dm;
    float* yr = y + (size_t)r * Dm;
    const int t = threadIdx.x;
    const float a = xr[t];
    const float b = xr[t + 256];
    float ss = a * a + b * b;
    #pragma unroll
    for (int off = 32; off > 0; off >>= 1) ss += __shfl_xor(ss, off, 64);
    __shared__ float ws4[4];
    if ((t & 63) == 0) ws4[t >> 6] = ss;
    __syncthreads();
    const float tot = ws4[0] + ws4[1] + ws4[2] + ws4[3];
    const float rs = rsqrtf(tot * (1.f / 512.f) + EPSR);
    yr[t] = a * rs * w[t];
    yr[t + 256] = b * rs * w[t + 256];
}

// =====================================================================
// Self-attention core: one block per (batch12, head), 256 query threads.
// qb: [NT, 512] (head slice h*64), kvb: [NT, 1024] (k at h*64, v at 512+h*64)
// Online softmax, K/V chunked 64 rows at a time through LDS.
// Writes output in-place into outb (may alias qb).
// =====================================================================
__global__ __launch_bounds__(256) void attn_self_kernel(
    const float* __restrict__ qb, const float* __restrict__ kvb,
    float* __restrict__ outb)
{
    const int bat = blockIdx.x >> 3;
    const int h = blockIdx.x & 7;
    const int i = threadIdx.x;     // query row
    __shared__ float k_lds[64][DH];
    __shared__ float v_lds[64][DH];

    float q[DH], o[DH];
    const float* qrow = qb + (size_t)(bat * Nn_ + i) * Dm + h * DH;
    #pragma unroll
    for (int d = 0; d < DH; d += 4) {
        float4 v = *(const float4*)(qrow + d);
        q[d] = v.x; q[d + 1] = v.y; q[d + 2] = v.z; q[d + 3] = v.w;
    }
    #pragma unroll
    for (int d = 0; d < DH; ++d) o[d] = 0.f;
    float mx = -1e30f, l = 0.f;

    for (int jc = 0; jc < Nn_; jc += 64) {
        __syncthreads();
        {
            const int jr = threadIdx.x >> 2;
            const int cc = (threadIdx.x & 3) * 16;
            const float* kr = kvb + (size_t)(bat * Nn_ + jc + jr) * 1024 + h * DH + cc;
            const float* vr = kr + Dm;
            #pragma unroll
            for (int c = 0; c < 16; c += 4) {
                *(float4*)&k_lds[jr][cc + c] = *(const float4*)(kr + c);
                *(float4*)&v_lds[jr][cc + c] = *(const float4*)(vr + c);
            }
        }
        __syncthreads();
        for (int j = 0; j < 64; ++j) {
            float s = 0.f;
            #pragma unroll
            for (int d = 0; d < DH; ++d) s = fmaf(q[d], k_lds[j][d], s);
            const float nm = fmaxf(mx, s);
            const float corr = __expf(mx - nm);
            const float p = __expf(s - nm);
            l = l * corr + p;
            #pragma unroll
            for (int d = 0; d < DH; ++d) {
                o[d] = o[d] * corr;
                o[d] = fmaf(p, v_lds[j][d], o[d]);
            }
            mx = nm;
        }
    }

    const float inv = 1.f / l;
    float* orow = outb + (size_t)(bat * Nn_ + i) * Dm + h * DH;
    #pragma unroll
    for (int d = 0; d < DH; d += 4) {
        float4 v;
        v.x = o[d] * inv; v.y = o[d + 1] * inv;
        v.z = o[d + 2] * inv; v.w = o[d + 3] * inv;
        *(float4*)(orow + d) = v;
    }
}

// =====================================================================
// Pooled attention: one wave per (query, head). M context rows.
// kvc rows indexed (m*512 + cb*256 + nn), 1024 wide (k | v).
// Query i pairs with context batch i//1536 and position i%256 (reference's
// q/ctx ordering mismatch, replicated exactly).
// =====================================================================
template <int M>
__global__ __launch_bounds__(256) void attn_pool_kernel(
    const float* __restrict__ qb, const float* __restrict__ kvc,
    float* __restrict__ outb)
{
    const int wid = (blockIdx.x << 2) + (threadIdx.x >> 6);
    const int lane = threadIdx.x & 63;
    const int iq = wid >> 3;
    const int h = wid & 7;
    const int cb = (iq >= 1536) ? 1 : 0;
    const int nn = iq & 255;
    const int rb = cb * 256 + nn;

    const float qd = qb[(size_t)iq * Dm + h * DH + lane];

    float s[M];
    #pragma unroll
    for (int m = 0; m < M; ++m) {
        float t = qd * kvc[(size_t)(m * 512 + rb) * 1024 + h * DH + lane];
        #pragma unroll
        for (int off = 32; off > 0; off >>= 1) t += __shfl_xor(t, off, 64);
        s[m] = t;
    }
    float mx = s[0];
    #pragma unroll
    for (int m = 1; m < M; ++m) mx = fmaxf(mx, s[m]);
    float l = 0.f, o = 0.f;
    #pragma unroll
    for (int m = 0; m < M; ++m) {
        const float p = __expf(s[m] - mx);
        l += p;
        o = fmaf(p, kvc[(size_t)(m * 512 + rb) * 1024 + 512 + h * DH + lane], o);
    }
    outb[(size_t)iq * Dm + h * DH + lane] = o / l;
}

// =====================================================================
// GLU * exact GELU, in-place on h [NT, 2730]: h[:, :1365] *= gelu(h[:, 1365:])
// =====================================================================
__global__ void glu_gelu_kernel(float* __restrict__ h)
{
    const int idx = blockIdx.x * blockDim.x + threadIdx.x;
    if (idx >= NT * DFF) return;
    const int i = idx / DFF;
    const int j = idx - i * DFF;
    float* row = h + (size_t)i * DFF2;
    const float sim = row[j];
    const float g = row[j + DFF];
    const float ge = 0.5f * g * (1.f + erff(g * 0.70710678118654752440f));
    row[j] = sim * ge;
}

// =====================================================================
// Broadcast initial tokens [2,256,512] -> tokens and msgs[0] [6,2,256,512]
// =====================================================================
__global__ void replicate_kernel(const float* __restrict__ src,
                                 float* __restrict__ tokens,
                                 float* __restrict__ msg0)
{
    const int idx = blockIdx.x * blockDim.x + threadIdx.x;
    if (idx >= NT * Dm) return;
    const float v = src[idx & (Bv * Nn_ * Dm - 1)];   // 262144 = 2^18
    tokens[idx] = v;
    msg0[idx] = v;
}

// =====================================================================
extern "C" void kernel_launch(void* const* d_in, const int* in_sizes, int n_in,
                              void* d_out, int out_size, void* d_ws, size_t ws_size,
                              hipStream_t stream)
{
    const float* tok_in       = (const float*)d_in[0];
    const float* attn_norm_w  = (const float*)d_in[1];
    const float* attn_wq      = (const float*)d_in[2];
    const float* attn_wkv     = (const float*)d_in[3];
    const float* attn_wo      = (const float*)d_in[4];
    const float* ff_norm_w    = (const float*)d_in[5];
    const float* ff_keys_w    = (const float*)d_in[6];
    const float* ff_keys_b    = (const float*)d_in[7];
    const float* ff_values_w  = (const float*)d_in[8];
    const float* ff_values_b  = (const float*)d_in[9];
    const float* res_norm_w   = (const float*)d_in[10];
    const float* res_wq       = (const float*)d_in[11];
    const float* res_wkv      = (const float*)d_in[12];
    const float* res_wo       = (const float*)d_in[13];

    float* ws = (float*)d_ws;
    float* msgs   = ws;                                   // 7 * NT * 512
    float* kvc    = msgs + (size_t)7 * NT * Dm;           // 42 * 512 * 1024
    float* tokens = kvc + (size_t)42 * 512 * 1024;        // NT * 512
    float* xn     = tokens + (size_t)NT * Dm;             // NT * 512
    float* qbuf   = xn + (size_t)NT * Dm;                 // NT * 512
    float* kvbuf  = qbuf + (size_t)NT * Dm;               // NT * 1024
    float* hbuf   = kvbuf + (size_t)NT * 1024;            // NT * 2730

    replicate_kernel<<<(NT * Dm + 255) / 256, 256, 0, stream>>>(tok_in, tokens, msgs);

    for (int e = 0; e < 3; ++e) {
        // ---------- self-attention (q from rmsnorm, kv from raw tokens) ----------
        rmsnorm_kernel<<<NT, 256, 0, stream>>>(tokens, attn_norm_w, xn);
        launch_gemm(xn, Dm, attn_wq, Dm, nullptr, qbuf, Dm, NT, Dm, Dm, stream);
        launch_gemm(tokens, Dm, attn_wkv, Dm, nullptr, kvbuf, 1024, NT, 1024, Dm, stream);
        attn_self_kernel<<<BBAT * NH, 256, 0, stream>>>(qbuf, kvbuf, qbuf);
        launch_gemm(qbuf, Dm, attn_wo, Dm, nullptr,
                    msgs + (size_t)(1 + 2 * e) * NT * Dm, Dm, NT, Dm, Dm, stream);

        // ---------- feedforward ----------
        rmsnorm_kernel<<<NT, 256, 0, stream>>>(tokens, ff_norm_w, xn);
        launch_gemm(xn, Dm, ff_keys_w, Dm, ff_keys_b, hbuf, DFF2, NT, DFF2, Dm, stream);
        glu_gelu_kernel<<<(NT * DFF + 255) / 256, 256, 0, stream>>>(hbuf);
        launch_gemm(hbuf, DFF2, ff_values_w, DFF, ff_values_b,
                    msgs + (size_t)(2 + 2 * e) * NT * Dm, Dm, NT, Dm, DFF, stream);

        // ---------- KV projection for new message sets (cached across exchanges) ----------
        const int s0 = (e == 0) ? 0 : (1 + 2 * e);
        const int nsets = (e == 0) ? 3 : 2;
        launch_gemm(msgs + (size_t)s0 * NT * Dm, Dm, res_wkv, Dm, nullptr,
                    kvc + (size_t)s0 * NT * 1024, 1024, nsets * NT, 1024, Dm, stream);

        // ---------- pooled attention ----------
        rmsnorm_kernel<<<NT, 256, 0, stream>>>(tokens, res_norm_w, xn);
        launch_gemm(xn, Dm, res_wq, Dm, nullptr, qbuf, Dm, NT, Dm, Dm, stream);
        if (e == 0)      attn_pool_kernel<18><<<NT * NH / 4, 256, 0, stream>>>(qbuf, kvc, qbuf);
        else if (e == 1) attn_pool_kernel<30><<<NT * NH / 4, 256, 0, stream>>>(qbuf, kvc, qbuf);
        else             attn_pool_kernel<42><<<NT * NH / 4, 256, 0, stream>>>(qbuf, kvc, qbuf);
        float* pdst = (e == 2) ? (float*)d_out : tokens;
        launch_gemm(qbuf, Dm, res_wo, Dm, nullptr, pdst, Dm, NT, Dm, Dm, stream);
    }
}

// Round 2
// 1779.907 us; speedup vs baseline: 1.7979x; 1.7979x over previous
//
#include <hip/hip_runtime.h>
#include <math.h>

// ---- problem constants ----
#define Dm   512
#define Nn_  256
#define Bv   2
#define NBLK 6
#define BBAT 12            // NBLK*Bv
#define NT   3072          // BBAT*Nn_
#define NH   8
#define DH   64
#define DFF  1365
#define DFF2 2730
#define KFF  1408          // DFF padded to mult of 32
#define NFF  2816          // DFF2 padded to mult of 128
#define EPSR 1.1920929e-07f

typedef __bf16 v8bf __attribute__((ext_vector_type(8)));
typedef float  v4f  __attribute__((ext_vector_type(4)));

__device__ inline unsigned short f2bf(float v) {
    unsigned int u = __float_as_uint(v);
    u = u + 0x7FFFu + ((u >> 16) & 1u);
    return (unsigned short)(u >> 16);
}
__device__ inline float bf2f(unsigned short s) {
    return __uint_as_float(((unsigned int)s) << 16);
}

__device__ inline void glds16(const void* g, void* l) {
    __builtin_amdgcn_global_load_lds((const __attribute__((address_space(1))) void*)g,
                                     (__attribute__((address_space(3))) void*)l, 16, 0, 0);
}

// =====================================================================
// Compensated bf16 MFMA GEMM (NT form): C[i,j] = sum_k A[i,k]*W[j,k] + bias[j]
// A,W given as bf16 hi plane + lo plane (offset Apl/Wpl elements).
// acc += Ah*Wh + Ah*Wl + Al*Wh  (error ~ Al*Wl ~ 2^-18 rel)
// M % 128 == 0, Npad % 128 == 0 (W buffer zero-padded), K % 32 == 0.
// 128x128 block tile, 4 waves, each wave a 64x64 sub-tile of 4x4 MFMAs.
// =====================================================================
template <int COMP>
__global__ __launch_bounds__(256) void gemm_bf(
    const unsigned short* __restrict__ A, long Apl, int lda,
    const unsigned short* __restrict__ W, long Wpl, int ldw,
    const float* __restrict__ bias,
    float* __restrict__ C, int ldc, int Nd, int K)
{
    constexpr int NTL = COMP ? 4 : 2;          // tiles staged: Ah,Wh[,Al,Wl]
    __shared__ unsigned short lds[NTL * 4096]; // each tile: 128 rows x 32 cols bf16 = 8KB
    const int tid = threadIdx.x;
    const int wid = tid >> 6;
    const int lane = tid & 63;
    const int wm = wid >> 1, wn = wid & 1;
    const int row16 = lane & 15, quad = lane >> 4;
    const long i0 = (long)blockIdx.x * 128;
    const long j0 = (long)blockIdx.y * 128;
    const int l4 = lane >> 2;        // row within a 16-row segment
    const int l2 = (lane & 3) * 8;   // k offset (shorts) within the 32-wide tile

    v4f acc[4][4];
    #pragma unroll
    for (int a = 0; a < 4; ++a)
        #pragma unroll
        for (int b = 0; b < 4; ++b) acc[a][b] = (v4f){0.f, 0.f, 0.f, 0.f};

    for (int k0 = 0; k0 < K; k0 += 32) {
        __syncthreads();
        // stage NTL tiles; each tile = 8 segments of (16 rows x 32 cols);
        // one wave-instr: 64 lanes x 16B = one segment.
        #pragma unroll
        for (int s = 0; s < NTL * 2; ++s) {
            const int sg = wid * (NTL * 2) + s;
            const int tile = sg >> 3;
            const int seg = sg & 7;
            const int row = seg * 16 + l4;
            const unsigned short* src;
            if (tile == 0)      src = A       + (i0 + row) * (long)lda + k0 + l2;
            else if (tile == 1) src = W       + (j0 + row) * (long)ldw + k0 + l2;
            else if (tile == 2) src = A + Apl + (i0 + row) * (long)lda + k0 + l2;
            else                src = W + Wpl + (j0 + row) * (long)ldw + k0 + l2;
            glds16(src, &lds[tile * 4096 + seg * 512]);
        }
        __syncthreads();

        v8bf af[4], al[4];
        #pragma unroll
        for (int mi = 0; mi < 4; ++mi) {
            const int aoff = (wm * 64 + mi * 16 + row16) * 32 + quad * 8;
            af[mi] = *(const v8bf*)&lds[aoff];
            if (COMP) al[mi] = *(const v8bf*)&lds[2 * 4096 + aoff];
        }
        #pragma unroll
        for (int nj = 0; nj < 4; ++nj) {
            const int boff = (wn * 64 + nj * 16 + row16) * 32 + quad * 8;
            v8bf bh = *(const v8bf*)&lds[4096 + boff];
            #pragma unroll
            for (int mi = 0; mi < 4; ++mi)
                acc[mi][nj] = __builtin_amdgcn_mfma_f32_16x16x32_bf16(af[mi], bh, acc[mi][nj], 0, 0, 0);
            if (COMP) {
                v8bf bl = *(const v8bf*)&lds[3 * 4096 + boff];
                #pragma unroll
                for (int mi = 0; mi < 4; ++mi) {
                    acc[mi][nj] = __builtin_amdgcn_mfma_f32_16x16x32_bf16(af[mi], bl, acc[mi][nj], 0, 0, 0);
                    acc[mi][nj] = __builtin_amdgcn_mfma_f32_16x16x32_bf16(al[mi], bh, acc[mi][nj], 0, 0, 0);
                }
            }
        }
    }

    // C/D layout (m89-verified): col = lane&15 (W side), row = quad*4 + reg (A side)
    #pragma unroll
    for (int nj = 0; nj < 4; ++nj) {
        const int col = (int)j0 + wn * 64 + nj * 16 + row16;
        if (col < Nd) {
            const float bv = bias ? bias[col] : 0.f;
            #pragma unroll
            for (int mi = 0; mi < 4; ++mi) {
                #pragma unroll
                for (int r = 0; r < 4; ++r) {
                    const long row = i0 + wm * 64 + mi * 16 + quad * 4 + r;
                    C[row * (long)ldc + col] = acc[mi][nj][r] + bv;
                }
            }
        }
    }
}

static void launch_gemm_bf(const unsigned short* A, long Apl, int lda,
                           const unsigned short* W, long Wpl, int ldw,
                           const float* bias, float* C, int ldc,
                           int M, int Npad, int Nd, int K, hipStream_t st)
{
    dim3 g(M / 128, Npad / 128);
    gemm_bf<1><<<g, 256, 0, st>>>(A, Apl, lda, W, Wpl, ldw, bias, C, ldc, Nd, K);
}

// =====================================================================
// fp32 -> bf16 hi/lo planes with optional row/col zero-padding
// =====================================================================
__global__ void cvt_hilo(const float* __restrict__ x, int Ms, int Ks, int Kp,
                         unsigned short* __restrict__ y, long plane, int total)
{
    const int idx = blockIdx.x * 256 + threadIdx.x;
    if (idx >= total) return;
    const int row = idx / Kp;
    const int col = idx - row * Kp;
    const float v = (row < Ms && col < Ks) ? x[(long)row * Ks + col] : 0.f;
    const unsigned short hi = f2bf(v);
    y[idx] = hi;
    y[idx + plane] = f2bf(v - bf2f(hi));
}

// =====================================================================
// RMSNorm fused with bf16 hi/lo output: one block per row of 512
// =====================================================================
__global__ __launch_bounds__(256) void rmsnorm_bf(
    const float* __restrict__ x, const float* __restrict__ w,
    unsigned short* __restrict__ y, long plane)
{
    const int r = blockIdx.x;
    const float* xr = x + (long)r * Dm;
    const int t = threadIdx.x;
    const float a = xr[t];
    const float b = xr[t + 256];
    float ss = a * a + b * b;
    #pragma unroll
    for (int off = 32; off > 0; off >>= 1) ss += __shfl_xor(ss, off, 64);
    __shared__ float w4[4];
    if ((t & 63) == 0) w4[t >> 6] = ss;
    __syncthreads();
    const float rs = rsqrtf((w4[0] + w4[1] + w4[2] + w4[3]) * (1.f / 512.f) + EPSR);
    const float ya = a * rs * w[t];
    const float yb = b * rs * w[t + 256];
    const long ia = (long)r * Dm + t, ib = ia + 256;
    const unsigned short ha = f2bf(ya);
    y[ia] = ha; y[ia + plane] = f2bf(ya - bf2f(ha));
    const unsigned short hb = f2bf(yb);
    y[ib] = hb; y[ib + plane] = f2bf(yb - bf2f(hb));
}

// =====================================================================
// GLU * exact GELU fused with bf16 hi/lo output padded to KFF cols.
// h: [NT, 2730]; y: [NT, 1408] hi/lo planes.
// =====================================================================
__global__ __launch_bounds__(256) void glu_gelu_bf(
    const float* __restrict__ h, unsigned short* __restrict__ y, long plane)
{
    const int r = blockIdx.x;
    const float* row = h + (long)r * DFF2;
    for (int c = threadIdx.x; c < KFF; c += 256) {
        float v = 0.f;
        if (c < DFF) {
            const float sim = row[c];
            const float g = row[c + DFF];
            v = sim * (0.5f * g * (1.f + erff(g * 0.70710678118654752440f)));
        }
        const long idx = (long)r * KFF + c;
        const unsigned short hi = f2bf(v);
        y[idx] = hi;
        y[idx + plane] = f2bf(v - bf2f(hi));
    }
}

// =====================================================================
// Self-attention: grid = BBAT*NH*4 (4 query-chunks of 64), block 256.
// 4 threads per query, each owning a 16-dim slice; dot via 2x shfl_xor.
// qb: [NT,512] (head slice h*64); kvb: [NT,1024] (k @ h*64, v @ 512+h*64).
// In-place safe (each block reads/writes only its own (rows x head-slice)).
// =====================================================================
__global__ __launch_bounds__(256) void attn_self_kernel(
    const float* __restrict__ qb, const float* __restrict__ kvb,
    float* __restrict__ outb)
{
    const int blk = blockIdx.x;
    const int qc = blk & 3;
    const int h = (blk >> 2) & 7;
    const int bat = blk >> 5;
    const int t = threadIdx.x;
    const int qi = t >> 2;           // query within chunk
    const int ds = (t & 3) * 16;     // d-slice start
    __shared__ float k_lds[64][DH];
    __shared__ float v_lds[64][DH];

    const long qrow = (long)(bat * Nn_ + qc * 64 + qi);
    const float* qp = qb + qrow * Dm + h * DH + ds;
    float q[16], o[16];
    #pragma unroll
    for (int d = 0; d < 16; d += 4) {
        const float4 v = *(const float4*)(qp + d);
        q[d] = v.x; q[d + 1] = v.y; q[d + 2] = v.z; q[d + 3] = v.w;
        o[d] = 0.f; o[d + 1] = 0.f; o[d + 2] = 0.f; o[d + 3] = 0.f;
    }
    float mx = -1e30f, l = 0.f;

    for (int jc = 0; jc < Nn_; jc += 64) {
        __syncthreads();
        {
            const int r = t >> 2;
            const int c = (t & 3) * 16;
            const float* kr = kvb + (long)(bat * Nn_ + jc + r) * 1024 + h * DH + c;
            #pragma unroll
            for (int cc = 0; cc < 16; cc += 4) {
                *(float4*)&k_lds[r][c + cc] = *(const float4*)(kr + cc);
                *(float4*)&v_lds[r][c + cc] = *(const float4*)(kr + 512 + cc);
            }
        }
        __syncthreads();
        for (int j = 0; j < 64; ++j) {
            float s = 0.f;
            #pragma unroll
            for (int d = 0; d < 16; ++d) s = fmaf(q[d], k_lds[j][ds + d], s);
            s += __shfl_xor(s, 1, 64);
            s += __shfl_xor(s, 2, 64);
            const float nm = fmaxf(mx, s);
            const float corr = __expf(mx - nm);
            const float p = __expf(s - nm);
            l = l * corr + p;
            #pragma unroll
            for (int d = 0; d < 16; ++d) o[d] = fmaf(p, v_lds[j][ds + d], o[d] * corr);
            mx = nm;
        }
    }
    const float inv = 1.f / l;
    float* op = outb + qrow * Dm + h * DH + ds;
    #pragma unroll
    for (int d = 0; d < 16; d += 4) {
        float4 v;
        v.x = o[d] * inv; v.y = o[d + 1] * inv;
        v.z = o[d + 2] * inv; v.w = o[d + 3] * inv;
        *(float4*)(op + d) = v;
    }
}

// =====================================================================
// Pooled attention: one wave per (query, head). M context rows.
// =====================================================================
template <int M>
__global__ __launch_bounds__(256) void attn_pool_kernel(
    const float* __restrict__ qb, const float* __restrict__ kvc,
    float* __restrict__ outb)
{
    const int wid = (blockIdx.x << 2) + (threadIdx.x >> 6);
    const int lane = threadIdx.x & 63;
    const int iq = wid >> 3;
    const int h = wid & 7;
    const int cb = (iq >= 1536) ? 1 : 0;
    const int nn = iq & 255;
    const int rb = cb * 256 + nn;

    const float qd = qb[(size_t)iq * Dm + h * DH + lane];

    float s[M];
    #pragma unroll
    for (int m = 0; m < M; ++m) {
        float t = qd * kvc[(size_t)(m * 512 + rb) * 1024 + h * DH + lane];
        #pragma unroll
        for (int off = 32; off > 0; off >>= 1) t += __shfl_xor(t, off, 64);
        s[m] = t;
    }
    float mx = s[0];
    #pragma unroll
    for (int m = 1; m < M; ++m) mx = fmaxf(mx, s[m]);
    float l = 0.f, o = 0.f;
    #pragma unroll
    for (int m = 0; m < M; ++m) {
        const float p = __expf(s[m] - mx);
        l += p;
        o = fmaf(p, kvc[(size_t)(m * 512 + rb) * 1024 + 512 + h * DH + lane], o);
    }
    outb[(size_t)iq * Dm + h * DH + lane] = o / l;
}

// =====================================================================
__global__ void replicate_kernel(const float* __restrict__ src,
                                 float* __restrict__ tokens,
                                 float* __restrict__ msg0)
{
    const int idx = blockIdx.x * blockDim.x + threadIdx.x;
    if (idx >= NT * Dm) return;
    const float v = src[idx & (Bv * Nn_ * Dm - 1)];
    tokens[idx] = v;
    msg0[idx] = v;
}

// =====================================================================
extern "C" void kernel_launch(void* const* d_in, const int* in_sizes, int n_in,
                              void* d_out, int out_size, void* d_ws, size_t ws_size,
                              hipStream_t stream)
{
    const float* tok_in       = (const float*)d_in[0];
    const float* attn_norm_w  = (const float*)d_in[1];
    const float* attn_wq      = (const float*)d_in[2];
    const float* attn_wkv     = (const float*)d_in[3];
    const float* attn_wo      = (const float*)d_in[4];
    const float* ff_norm_w    = (const float*)d_in[5];
    const float* ff_keys_w    = (const float*)d_in[6];
    const float* ff_keys_b    = (const float*)d_in[7];
    const float* ff_values_w  = (const float*)d_in[8];
    const float* ff_values_b  = (const float*)d_in[9];
    const float* res_norm_w   = (const float*)d_in[10];
    const float* res_wq       = (const float*)d_in[11];
    const float* res_wkv      = (const float*)d_in[12];
    const float* res_wo       = (const float*)d_in[13];

    float* ws = (float*)d_ws;
    float* msgs   = ws;                                    // 7*NT*512
    float* kvc    = msgs + 7L * NT * Dm;                   // 42*512*1024
    float* tokens = kvc + 42L * 512 * 1024;                // NT*512
    float* qbuf   = tokens + (long)NT * Dm;                // NT*512
    float* kvbuf  = qbuf + (long)NT * Dm;                  // NT*1024
    float* hbuf   = kvbuf + (long)NT * 1024;               // NT*2730

    unsigned short* us = (unsigned short*)(hbuf + (long)NT * DFF2);
    const long apl = (long)NT * Dm;        // activation plane (elements)
    const long hpl = (long)NT * KFF;
    const long w1 = 512L * 512, w2 = 1024L * 512, w3 = (long)NFF * 512, w4 = 512L * KFF;
    unsigned short* abf  = us; us += 2 * apl;   // generic activation hi/lo
    unsigned short* xbf  = us; us += 2 * apl;   // rmsnorm output hi/lo
    unsigned short* hbf  = us; us += 2 * hpl;   // glu output hi/lo
    unsigned short* wqb  = us; us += 2 * w1;
    unsigned short* wkvb = us; us += 2 * w2;
    unsigned short* wob  = us; us += 2 * w1;
    unsigned short* fkb  = us; us += 2 * w3;
    unsigned short* fvb  = us; us += 2 * w4;
    unsigned short* rqb  = us; us += 2 * w1;
    unsigned short* rkvb = us; us += 2 * w2;
    unsigned short* rob  = us; us += 2 * w1;

    // ---- weight conversions (cheap; every call for graph-capture safety) ----
    auto cvtw = [&](const float* src, int Ms, int Ks, int Kp, int Mpad,
                    unsigned short* dst, long pl) {
        const int tot = Mpad * Kp;
        cvt_hilo<<<(tot + 255) / 256, 256, 0, stream>>>(src, Ms, Ks, Kp, dst, pl, tot);
    };
    cvtw(attn_wq,     512,  512,  512, 512,  wqb,  w1);
    cvtw(attn_wkv,    1024, 512,  512, 1024, wkvb, w2);
    cvtw(attn_wo,     512,  512,  512, 512,  wob,  w1);
    cvtw(ff_keys_w,   DFF2, 512,  512, NFF,  fkb,  w3);
    cvtw(ff_values_w, 512,  DFF,  KFF, 512,  fvb,  w4);
    cvtw(res_wq,      512,  512,  512, 512,  rqb,  w1);
    cvtw(res_wkv,     1024, 512,  512, 1024, rkvb, w2);
    cvtw(res_wo,      512,  512,  512, 512,  rob,  w1);

    replicate_kernel<<<(NT * Dm + 255) / 256, 256, 0, stream>>>(tok_in, tokens, msgs);

    const int NCVT = (NT * Dm + 255) / 256;
    for (int e = 0; e < 3; ++e) {
        // ---------- self-attention ----------
        rmsnorm_bf<<<NT, 256, 0, stream>>>(tokens, attn_norm_w, xbf, apl);
        launch_gemm_bf(xbf, apl, 512, wqb, w1, 512, nullptr, qbuf, 512, NT, 512, 512, 512, stream);
        cvt_hilo<<<NCVT, 256, 0, stream>>>(tokens, NT, 512, 512, abf, apl, NT * Dm);
        launch_gemm_bf(abf, apl, 512, wkvb, w2, 512, nullptr, kvbuf, 1024, NT, 1024, 1024, 512, stream);
        attn_self_kernel<<<BBAT * NH * 4, 256, 0, stream>>>(qbuf, kvbuf, qbuf);
        cvt_hilo<<<NCVT, 256, 0, stream>>>(qbuf, NT, 512, 512, abf, apl, NT * Dm);
        launch_gemm_bf(abf, apl, 512, wob, w1, 512, nullptr,
                       msgs + (1 + 2 * e) * (long)NT * Dm, 512, NT, 512, 512, 512, stream);

        // ---------- feedforward ----------
        rmsnorm_bf<<<NT, 256, 0, stream>>>(tokens, ff_norm_w, xbf, apl);
        launch_gemm_bf(xbf, apl, 512, fkb, w3, 512, ff_keys_b, hbuf, DFF2, NT, NFF, DFF2, 512, stream);
        glu_gelu_bf<<<NT, 256, 0, stream>>>(hbuf, hbf, hpl);
        launch_gemm_bf(hbf, hpl, KFF, fvb, w4, KFF, ff_values_b,
                       msgs + (2 + 2 * e) * (long)NT * Dm, 512, NT, 512, 512, KFF, stream);

        // ---------- KV projection for new message sets (cached across exchanges) ----------
        const int s0 = (e == 0) ? 0 : (1 + 2 * e);
        const int ns = (e == 0) ? 3 : 2;
        for (int s = s0; s < s0 + ns; ++s) {
            cvt_hilo<<<NCVT, 256, 0, stream>>>(msgs + (long)s * NT * Dm, NT, 512, 512, abf, apl, NT * Dm);
            launch_gemm_bf(abf, apl, 512, rkvb, w2, 512, nullptr,
                           kvc + (long)s * NT * 1024, 1024, NT, 1024, 1024, 512, stream);
        }

        // ---------- pooled attention ----------
        rmsnorm_bf<<<NT, 256, 0, stream>>>(tokens, res_norm_w, xbf, apl);
        launch_gemm_bf(xbf, apl, 512, rqb, w1, 512, nullptr, qbuf, 512, NT, 512, 512, 512, stream);
        if (e == 0)      attn_pool_kernel<18><<<NT * NH / 4, 256, 0, stream>>>(qbuf, kvc, qbuf);
        else if (e == 1) attn_pool_kernel<30><<<NT * NH / 4, 256, 0, stream>>>(qbuf, kvc, qbuf);
        else             attn_pool_kernel<42><<<NT * NH / 4, 256, 0, stream>>>(qbuf, kvc, qbuf);
        cvt_hilo<<<NCVT, 256, 0, stream>>>(qbuf, NT, 512, 512, abf, apl, NT * Dm);
        float* pdst = (e == 2) ? (float*)d_out : tokens;
        launch_gemm_bf(abf, apl, 512, rob, w1, 512, nullptr, pdst, 512, NT, 512, 512, 512, stream);
    }
}

// Round 3
// 1610.947 us; speedup vs baseline: 1.9865x; 1.1049x over previous
//
#include <hip/hip_runtime.h>
#include <math.h>

// ---- problem constants ----
#define Dm   512
#define Nn_  256
#define Bv   2
#define NBLK 6
#define BBAT 12            // NBLK*Bv
#define NT   3072          // BBAT*Nn_
#define NH   8
#define DH   64
#define DFF  1365
#define DFF2 2730
#define KFF  1408          // DFF padded to mult of 32
#define NFF  2816          // DFF2 padded to mult of 128
#define MMAX 42            // max pooled-context messages
#define EPSR 1.1920929e-07f

typedef __bf16 v8bf __attribute__((ext_vector_type(8)));
typedef float  v4f  __attribute__((ext_vector_type(4)));

__device__ inline unsigned short f2bf(float v) {
    unsigned int u = __float_as_uint(v);
    u = u + 0x7FFFu + ((u >> 16) & 1u);
    return (unsigned short)(u >> 16);
}
__device__ inline float bf2f(unsigned short s) {
    return __uint_as_float(((unsigned int)s) << 16);
}

__device__ inline void glds16(const void* g, void* l) {
    __builtin_amdgcn_global_load_lds((const __attribute__((address_space(1))) void*)g,
                                     (__attribute__((address_space(3))) void*)l, 16, 0, 0);
}

// =====================================================================
// Compensated bf16 MFMA GEMM (NT): C[i,j] = sum_k A[i,k]*W[j,k] (+bias[j])
// A,W are bf16 hi planes with lo planes at +Apl/+Wpl elements.
// acc += Ah*Wh + Ah*Wl + Al*Wh.
// MODE 0: fp32 C.  MODE 1: bf16 hi/lo Cbf only.  MODE 2: both.
// MODE 3: fp32 with pooled-ctx row remap:
//   r -> srel=r/3072, rr=r%3072, orow=(rr&511)*MMAX + mbase + srel*6 + (rr>>9)
// M%128==0, Npad%128==0 (W zero-padded), K%32==0.
// =====================================================================
template <int MODE>
__global__ __launch_bounds__(256) void gemm_bf(
    const unsigned short* __restrict__ A, long Apl, int lda,
    const unsigned short* __restrict__ W, long Wpl, int ldw,
    const float* __restrict__ bias,
    float* __restrict__ C, int ldc, int Nd,
    unsigned short* __restrict__ Cbf, long bfpl, int mbase, int K)
{
    __shared__ unsigned short lds[4 * 4096]; // 4 tiles: Ah,Wh,Al,Wl (128x32 bf16)
    const int tid = threadIdx.x;
    const int wid = tid >> 6;
    const int lane = tid & 63;
    const int wm = wid >> 1, wn = wid & 1;
    const int row16 = lane & 15, quad = lane >> 4;
    const long i0 = (long)blockIdx.x * 128;
    const long j0 = (long)blockIdx.y * 128;
    const int l4 = lane >> 2;
    const int l2 = (lane & 3) * 8;

    v4f acc[4][4];
    #pragma unroll
    for (int a = 0; a < 4; ++a)
        #pragma unroll
        for (int b = 0; b < 4; ++b) acc[a][b] = (v4f){0.f, 0.f, 0.f, 0.f};

    for (int k0 = 0; k0 < K; k0 += 32) {
        __syncthreads();
        #pragma unroll
        for (int s = 0; s < 8; ++s) {
            const int sg = wid * 8 + s;
            const int tile = sg >> 3;
            const int seg = sg & 7;
            const int row = seg * 16 + l4;
            const unsigned short* src;
            if (tile == 0)      src = A       + (i0 + row) * (long)lda + k0 + l2;
            else if (tile == 1) src = W       + (j0 + row) * (long)ldw + k0 + l2;
            else if (tile == 2) src = A + Apl + (i0 + row) * (long)lda + k0 + l2;
            else                src = W + Wpl + (j0 + row) * (long)ldw + k0 + l2;
            glds16(src, &lds[tile * 4096 + seg * 512]);
        }
        __syncthreads();

        v8bf af[4], al[4];
        #pragma unroll
        for (int mi = 0; mi < 4; ++mi) {
            const int aoff = (wm * 64 + mi * 16 + row16) * 32 + quad * 8;
            af[mi] = *(const v8bf*)&lds[aoff];
            al[mi] = *(const v8bf*)&lds[2 * 4096 + aoff];
        }
        #pragma unroll
        for (int nj = 0; nj < 4; ++nj) {
            const int boff = (wn * 64 + nj * 16 + row16) * 32 + quad * 8;
            v8bf bh = *(const v8bf*)&lds[4096 + boff];
            v8bf bl = *(const v8bf*)&lds[3 * 4096 + boff];
            #pragma unroll
            for (int mi = 0; mi < 4; ++mi) {
                acc[mi][nj] = __builtin_amdgcn_mfma_f32_16x16x32_bf16(af[mi], bh, acc[mi][nj], 0, 0, 0);
                acc[mi][nj] = __builtin_amdgcn_mfma_f32_16x16x32_bf16(af[mi], bl, acc[mi][nj], 0, 0, 0);
                acc[mi][nj] = __builtin_amdgcn_mfma_f32_16x16x32_bf16(al[mi], bh, acc[mi][nj], 0, 0, 0);
            }
        }
    }

    // C/D layout: col = lane&15 (W side), row = quad*4 + reg (A side)
    #pragma unroll
    for (int nj = 0; nj < 4; ++nj) {
        const int col = (int)j0 + wn * 64 + nj * 16 + row16;
        if (col < Nd) {
            const float bv = bias ? bias[col] : 0.f;
            #pragma unroll
            for (int mi = 0; mi < 4; ++mi) {
                #pragma unroll
                for (int r = 0; r < 4; ++r) {
                    const long row = i0 + wm * 64 + mi * 16 + quad * 4 + r;
                    const float v = acc[mi][nj][r] + bv;
                    if (MODE == 0) {
                        C[row * (long)ldc + col] = v;
                    } else if (MODE == 1) {
                        const long idx = row * (long)ldc + col;
                        const unsigned short hi = f2bf(v);
                        Cbf[idx] = hi; Cbf[idx + bfpl] = f2bf(v - bf2f(hi));
                    } else if (MODE == 2) {
                        const long idx = row * (long)ldc + col;
                        C[idx] = v;
                        const unsigned short hi = f2bf(v);
                        Cbf[idx] = hi; Cbf[idx + bfpl] = f2bf(v - bf2f(hi));
                    } else {
                        const int srel = (int)(row / 3072);
                        const int rr = (int)row - srel * 3072;
                        const long orow = (long)(rr & 511) * MMAX + mbase + srel * 6 + (rr >> 9);
                        C[orow * 1024 + col] = v;
                    }
                }
            }
        }
    }
}

// =====================================================================
// fp32 -> bf16 hi/lo planes (weights only), with zero-padding
// =====================================================================
__global__ void cvt_hilo(const float* __restrict__ x, int Ms, int Ks, int Kp,
                         unsigned short* __restrict__ y, long plane, int total)
{
    const int idx = blockIdx.x * 256 + threadIdx.x;
    if (idx >= total) return;
    const int row = idx / Kp;
    const int col = idx - row * Kp;
    const float v = (row < Ms && col < Ks) ? x[(long)row * Ks + col] : 0.f;
    const unsigned short hi = f2bf(v);
    y[idx] = hi;
    y[idx + plane] = f2bf(v - bf2f(hi));
}

// =====================================================================
// RMSNorm fused with bf16 hi/lo output: one block per row of 512
// =====================================================================
__global__ __launch_bounds__(256) void rmsnorm_bf(
    const float* __restrict__ x, const float* __restrict__ w,
    unsigned short* __restrict__ y, long plane)
{
    const int r = blockIdx.x;
    const float* xr = x + (long)r * Dm;
    const int t = threadIdx.x;
    const float a = xr[t];
    const float b = xr[t + 256];
    float ss = a * a + b * b;
    #pragma unroll
    for (int off = 32; off > 0; off >>= 1) ss += __shfl_xor(ss, off, 64);
    __shared__ float w4[4];
    if ((t & 63) == 0) w4[t >> 6] = ss;
    __syncthreads();
    const float rs = rsqrtf((w4[0] + w4[1] + w4[2] + w4[3]) * (1.f / 512.f) + EPSR);
    const float ya = a * rs * w[t];
    const float yb = b * rs * w[t + 256];
    const long ia = (long)r * Dm + t, ib = ia + 256;
    const unsigned short ha = f2bf(ya);
    y[ia] = ha; y[ia + plane] = f2bf(ya - bf2f(ha));
    const unsigned short hb = f2bf(yb);
    y[ib] = hb; y[ib + plane] = f2bf(yb - bf2f(hb));
}

// =====================================================================
// GLU * exact GELU fused with bf16 hi/lo output padded to KFF cols.
// =====================================================================
__global__ __launch_bounds__(256) void glu_gelu_bf(
    const float* __restrict__ h, unsigned short* __restrict__ y, long plane)
{
    const int r = blockIdx.x;
    const float* row = h + (long)r * DFF2;
    for (int c = threadIdx.x; c < KFF; c += 256) {
        float v = 0.f;
        if (c < DFF) {
            const float sim = row[c];
            const float g = row[c + DFF];
            v = sim * (0.5f * g * (1.f + erff(g * 0.70710678118654752440f)));
        }
        const long idx = (long)r * KFF + c;
        const unsigned short hi = f2bf(v);
        y[idx] = hi;
        y[idx + plane] = f2bf(v - bf2f(hi));
    }
}

// =====================================================================
// Self-attention: grid = BBAT*NH*4 (4 query-chunks of 64), block 256.
// 4 threads per query, each owning a 16-dim slice. Output: bf16 hi/lo.
// =====================================================================
__global__ __launch_bounds__(256) void attn_self_kernel(
    const float* __restrict__ qb, const float* __restrict__ kvb,
    unsigned short* __restrict__ outbf, long plane)
{
    const int blk = blockIdx.x;
    const int qc = blk & 3;
    const int h = (blk >> 2) & 7;
    const int bat = blk >> 5;
    const int t = threadIdx.x;
    const int qi = t >> 2;
    const int ds = (t & 3) * 16;
    __shared__ float k_lds[64][DH];
    __shared__ float v_lds[64][DH];

    const long qrow = (long)(bat * Nn_ + qc * 64 + qi);
    const float* qp = qb + qrow * Dm + h * DH + ds;
    float q[16], o[16];
    #pragma unroll
    for (int d = 0; d < 16; d += 4) {
        const float4 v = *(const float4*)(qp + d);
        q[d] = v.x; q[d + 1] = v.y; q[d + 2] = v.z; q[d + 3] = v.w;
        o[d] = 0.f; o[d + 1] = 0.f; o[d + 2] = 0.f; o[d + 3] = 0.f;
    }
    float mx = -1e30f, l = 0.f;

    for (int jc = 0; jc < Nn_; jc += 64) {
        __syncthreads();
        {
            const int r = t >> 2;
            const int c = (t & 3) * 16;
            const float* kr = kvb + (long)(bat * Nn_ + jc + r) * 1024 + h * DH + c;
            #pragma unroll
            for (int cc = 0; cc < 16; cc += 4) {
                *(float4*)&k_lds[r][c + cc] = *(const float4*)(kr + cc);
                *(float4*)&v_lds[r][c + cc] = *(const float4*)(kr + 512 + cc);
            }
        }
        __syncthreads();
        for (int j = 0; j < 64; ++j) {
            float s = 0.f;
            #pragma unroll
            for (int d = 0; d < 16; ++d) s = fmaf(q[d], k_lds[j][ds + d], s);
            s += __shfl_xor(s, 1, 64);
            s += __shfl_xor(s, 2, 64);
            const float nm = fmaxf(mx, s);
            const float corr = __expf(mx - nm);
            const float p = __expf(s - nm);
            l = l * corr + p;
            #pragma unroll
            for (int d = 0; d < 16; ++d) o[d] = fmaf(p, v_lds[j][ds + d], o[d] * corr);
            mx = nm;
        }
    }
    const float inv = 1.f / l;
    const long obase = qrow * Dm + h * DH + ds;
    #pragma unroll
    for (int d = 0; d < 16; ++d) {
        const float v = o[d] * inv;
        const unsigned short hi = f2bf(v);
        outbf[obase + d] = hi;
        outbf[obase + d + plane] = f2bf(v - bf2f(hi));
    }
}

// =====================================================================
// Pooled attention: one block per (rb, head), 384 threads = 6 waves,
// one wave per query sharing rb. K/V slice staged once in LDS.
// kvc2 row layout: [rb*MMAX + m][1024] (k @ h*64, v @ 512+h*64).
// Output: bf16 hi/lo.
// =====================================================================
template <int M>
__global__ __launch_bounds__(384) void attn_pool_kernel(
    const float* __restrict__ qb, const float* __restrict__ kvc2,
    unsigned short* __restrict__ outbf, long plane)
{
    const int rb = blockIdx.x >> 3;
    const int h = blockIdx.x & 7;
    __shared__ float k_lds[M][DH];
    __shared__ float v_lds[M][DH];
    const int t = threadIdx.x;

    for (int idx = t * 4; idx < M * 128; idx += 384 * 4) {
        const int m = idx >> 7, c = idx & 127;
        const float* src = kvc2 + ((long)rb * MMAX + m) * 1024 +
                           (c < 64 ? h * DH + c : 448 + h * DH + c);
        const float4 val = *(const float4*)src;
        if (c < 64) *(float4*)&k_lds[m][c] = val;
        else        *(float4*)&v_lds[m][c - 64] = val;
    }
    __syncthreads();

    const int w = t >> 6;          // query 0..5
    const int lane = t & 63;
    const int cb = rb >> 8, nn = rb & 255;
    const long iq = (long)cb * 1536 + nn + w * 256;
    const float qd = qb[iq * Dm + h * DH + lane];

    float s[M];
    #pragma unroll
    for (int m = 0; m < M; ++m) {
        float x = qd * k_lds[m][lane];
        #pragma unroll
        for (int off = 32; off > 0; off >>= 1) x += __shfl_xor(x, off, 64);
        s[m] = x;
    }
    float mx = s[0];
    #pragma unroll
    for (int m = 1; m < M; ++m) mx = fmaxf(mx, s[m]);
    float l = 0.f, o = 0.f;
    #pragma unroll
    for (int m = 0; m < M; ++m) {
        const float p = __expf(s[m] - mx);
        l += p;
        o = fmaf(p, v_lds[m][lane], o);
    }
    const float res = o / l;
    const long oidx = iq * Dm + h * DH + lane;
    const unsigned short hi = f2bf(res);
    outbf[oidx] = hi;
    outbf[oidx + plane] = f2bf(res - bf2f(hi));
}

// =====================================================================
// Broadcast tokens [2,256,512] -> tokens fp32, tokens_bf hi/lo, msgs_bf set0
// =====================================================================
__global__ void replicate_kernel(const float* __restrict__ src,
                                 float* __restrict__ tokens,
                                 unsigned short* __restrict__ tokbf, long tpl,
                                 unsigned short* __restrict__ msg0, long mpl)
{
    const int idx = blockIdx.x * blockDim.x + threadIdx.x;
    if (idx >= NT * Dm) return;
    const float v = src[idx & (Bv * Nn_ * Dm - 1)];
    tokens[idx] = v;
    const unsigned short hi = f2bf(v);
    const unsigned short lo = f2bf(v - bf2f(hi));
    tokbf[idx] = hi; tokbf[idx + tpl] = lo;
    msg0[idx] = hi; msg0[idx + mpl] = lo;
}

// =====================================================================
extern "C" void kernel_launch(void* const* d_in, const int* in_sizes, int n_in,
                              void* d_out, int out_size, void* d_ws, size_t ws_size,
                              hipStream_t stream)
{
    const float* tok_in       = (const float*)d_in[0];
    const float* attn_norm_w  = (const float*)d_in[1];
    const float* attn_wq      = (const float*)d_in[2];
    const float* attn_wkv     = (const float*)d_in[3];
    const float* attn_wo      = (const float*)d_in[4];
    const float* ff_norm_w    = (const float*)d_in[5];
    const float* ff_keys_w    = (const float*)d_in[6];
    const float* ff_keys_b    = (const float*)d_in[7];
    const float* ff_values_w  = (const float*)d_in[8];
    const float* ff_values_b  = (const float*)d_in[9];
    const float* res_norm_w   = (const float*)d_in[10];
    const float* res_wq       = (const float*)d_in[11];
    const float* res_wkv      = (const float*)d_in[12];
    const float* res_wo       = (const float*)d_in[13];

    float* ws = (float*)d_ws;
    float* kvc2   = ws;                                  // 512*42*1024
    float* tokens = kvc2 + 512L * MMAX * 1024;           // NT*512
    float* qbuf   = tokens + (long)NT * Dm;              // NT*512
    float* kvbuf  = qbuf + (long)NT * Dm;                // NT*1024
    float* hbuf   = kvbuf + (long)NT * 1024;             // NT*2730

    unsigned short* us = (unsigned short*)(hbuf + (long)NT * DFF2);
    const long apl = (long)NT * Dm;          // activation plane
    const long mpl = 7L * NT * Dm;           // msgs plane (7 sets)
    const long hpl = (long)NT * KFF;
    const long w1 = 512L * 512, w2 = 1024L * 512, w3 = (long)NFF * 512, w4 = 512L * KFF;
    unsigned short* msgs_bf = us; us += 2 * mpl;  // hi[7][NT][512] | lo[...]
    unsigned short* tokbf   = us; us += 2 * apl;
    unsigned short* xbf     = us; us += 2 * apl;
    unsigned short* abf     = us; us += 2 * apl;
    unsigned short* hbf     = us; us += 2 * hpl;
    unsigned short* wqb  = us; us += 2 * w1;
    unsigned short* wkvb = us; us += 2 * w2;
    unsigned short* wob  = us; us += 2 * w1;
    unsigned short* fkb  = us; us += 2 * w3;
    unsigned short* fvb  = us; us += 2 * w4;
    unsigned short* rqb  = us; us += 2 * w1;
    unsigned short* rkvb = us; us += 2 * w2;
    unsigned short* rob  = us; us += 2 * w1;

    auto cvtw = [&](const float* src, int Ms, int Ks, int Kp, int Mpad,
                    unsigned short* dst, long pl) {
        const int tot = Mpad * Kp;
        cvt_hilo<<<(tot + 255) / 256, 256, 0, stream>>>(src, Ms, Ks, Kp, dst, pl, tot);
    };
    cvtw(attn_wq,     512,  512,  512, 512,  wqb,  w1);
    cvtw(attn_wkv,    1024, 512,  512, 1024, wkvb, w2);
    cvtw(attn_wo,     512,  512,  512, 512,  wob,  w1);
    cvtw(ff_keys_w,   DFF2, 512,  512, NFF,  fkb,  w3);
    cvtw(ff_values_w, 512,  DFF,  KFF, 512,  fvb,  w4);
    cvtw(res_wq,      512,  512,  512, 512,  rqb,  w1);
    cvtw(res_wkv,     1024, 512,  512, 1024, rkvb, w2);
    cvtw(res_wo,      512,  512,  512, 512,  rob,  w1);

    replicate_kernel<<<(NT * Dm + 255) / 256, 256, 0, stream>>>(
        tok_in, tokens, tokbf, apl, msgs_bf, mpl);

    // GEMM launch helpers
    auto g_f32 = [&](const unsigned short* A, int lda, const unsigned short* W,
                     long Wpl, int ldw, const float* bias, float* C, int ldc,
                     int M, int Npad, int Nd, int K) {
        dim3 g(M / 128, Npad / 128);
        gemm_bf<0><<<g, 256, 0, stream>>>(A, apl, lda, W, Wpl, ldw, bias, C, ldc, Nd,
                                          nullptr, 0, 0, K);
    };

    for (int e = 0; e < 3; ++e) {
        // ---------- self-attention ----------
        rmsnorm_bf<<<NT, 256, 0, stream>>>(tokens, attn_norm_w, xbf, apl);
        g_f32(xbf, 512, wqb, w1, 512, nullptr, qbuf, 512, NT, 512, 512, 512);
        g_f32(tokbf, 512, wkvb, w2, 512, nullptr, kvbuf, 1024, NT, 1024, 1024, 512);
        attn_self_kernel<<<BBAT * NH * 4, 256, 0, stream>>>(qbuf, kvbuf, abf, apl);
        {   // wo -> msgs_bf set (1+2e), bf-only output
            dim3 g(NT / 128, 4);
            gemm_bf<1><<<g, 256, 0, stream>>>(abf, apl, 512, wob, w1, 512, nullptr,
                                              nullptr, 512, 512,
                                              msgs_bf + (1 + 2 * e) * (long)NT * Dm, mpl, 0, 512);
        }

        // ---------- feedforward ----------
        rmsnorm_bf<<<NT, 256, 0, stream>>>(tokens, ff_norm_w, xbf, apl);
        g_f32(xbf, 512, fkb, w3, 512, ff_keys_b, hbuf, DFF2, NT, NFF, DFF2, 512);
        glu_gelu_bf<<<NT, 256, 0, stream>>>(hbuf, hbf, hpl);
        {   // ffv -> msgs_bf set (2+2e), bf-only output
            dim3 g(NT / 128, 4);
            gemm_bf<1><<<g, 256, 0, stream>>>(hbf, hpl, KFF, fvb, w4, KFF, ff_values_b,
                                              nullptr, 512, 512,
                                              msgs_bf + (2 + 2 * e) * (long)NT * Dm, mpl, 0, KFF);
        }

        // ---------- KV projection for new message sets (batched, remapped) ----------
        const int s0 = (e == 0) ? 0 : (1 + 2 * e);
        const int ns = (e == 0) ? 3 : 2;
        {
            dim3 g(ns * NT / 128, 8);
            gemm_bf<3><<<g, 256, 0, stream>>>(msgs_bf + (long)s0 * NT * Dm, mpl, 512,
                                              rkvb, w2, 512, nullptr,
                                              kvc2, 1024, 1024, nullptr, 0, s0 * 6, 512);
        }

        // ---------- pooled attention ----------
        rmsnorm_bf<<<NT, 256, 0, stream>>>(tokens, res_norm_w, xbf, apl);
        g_f32(xbf, 512, rqb, w1, 512, nullptr, qbuf, 512, NT, 512, 512, 512);
        if (e == 0)      attn_pool_kernel<18><<<512 * NH, 384, 0, stream>>>(qbuf, kvc2, abf, apl);
        else if (e == 1) attn_pool_kernel<30><<<512 * NH, 384, 0, stream>>>(qbuf, kvc2, abf, apl);
        else             attn_pool_kernel<42><<<512 * NH, 384, 0, stream>>>(qbuf, kvc2, abf, apl);
        if (e < 2) {
            dim3 g(NT / 128, 4);
            gemm_bf<2><<<g, 256, 0, stream>>>(abf, apl, 512, rob, w1, 512, nullptr,
                                              tokens, 512, 512, tokbf, apl, 0, 512);
        } else {
            g_f32(abf, 512, rob, w1, 512, nullptr, (float*)d_out, 512, NT, 512, 512, 512);
        }
    }
}

// Round 4
// 1035.169 us; speedup vs baseline: 3.0914x; 1.5562x over previous
//
#include <hip/hip_runtime.h>
#include <math.h>

// ---- problem constants ----
#define Dm   512
#define Nn_  256
#define Bv   2
#define NBLK 6
#define BBAT 12            // NBLK*Bv
#define NT   3072          // BBAT*Nn_
#define NH   8
#define DH   64
#define DFF  1365
#define DFF2 2730
#define KFF  1408          // DFF padded to mult of 32 (ffv K)
#define NFF  2816          // DFF2 padded to mult of 128 (ffk N)
#define MMAX 42            // max pooled-context messages
#define EPSR 1.1920929e-07f

typedef __bf16 v8bf __attribute__((ext_vector_type(8)));
typedef float  v4f  __attribute__((ext_vector_type(4)));

__device__ inline unsigned short f2bf(float v) {
    unsigned int u = __float_as_uint(v);
    u = u + 0x7FFFu + ((u >> 16) & 1u);
    return (unsigned short)(u >> 16);
}
__device__ inline float bf2f(unsigned short s) {
    return __uint_as_float(((unsigned int)s) << 16);
}

__device__ inline void glds16(const void* g, void* l) {
    __builtin_amdgcn_global_load_lds((const __attribute__((address_space(1))) void*)g,
                                     (__attribute__((address_space(3))) void*)l, 16, 0, 0);
}

// =====================================================================
// Multi-GEMM dispatcher. Each block picks one of up to 3 descriptors by
// linear block id, then runs a compensated bf16 MFMA GEMM tile:
//   C[i,j] = sum_k A[i,k]*W[j,k] (+bias[j]),  acc += Ah*Wh + Ah*Wl + Al*Wh
// modes: 0 = fp32 C; 1 = bf16 hi/lo Cbf; 2 = both; 3 = fp32 pooled-ctx remap
// BM in {64,128}; BN = 128. K % 32 == 0. A,W hi planes + lo at +Apl/+Wpl.
// =====================================================================
struct GDesc {
    const unsigned short* A;
    const unsigned short* W;
    const float* bias;
    float* C;
    unsigned short* Cbf;
    long Apl, Wpl, bfpl;
    int lda, ldw, ldc, Nd, mbase, K, mode, nbx;
};

template <int BM>
__global__ __launch_bounds__(256) void mega_gemm(GDesc d0, GDesc d1, GDesc d2,
                                                 int n0, int n01)
{
    constexpr int MI = BM / 32;          // 16-row acc tiles per wave (m dir)
    constexpr int ASEG = BM / 16;        // 16-row segments per A plane
    constexpr int NSEG = 2 * ASEG + 16;  // total staging segments
    constexpr int AH = 0, AL = BM * 32, WH = 2 * BM * 32, WL = 2 * BM * 32 + 4096;
    __shared__ unsigned short lds[2 * BM * 32 + 2 * 4096];

    GDesc d; int lb = blockIdx.x;
    if (lb < n0) d = d0;
    else if (lb < n01) { d = d1; lb -= n0; }
    else { d = d2; lb -= n01; }
    const int bx = lb % d.nbx;
    const int by = lb / d.nbx;

    const int tid = threadIdx.x;
    const int wid = tid >> 6;
    const int lane = tid & 63;
    const int wm = wid >> 1, wn = wid & 1;
    const int row16 = lane & 15, quad = lane >> 4;
    const long i0 = (long)bx * BM;
    const long j0 = (long)by * 128;
    const int l4 = lane >> 2;        // row within 16-row segment
    const int l2 = (lane & 3) * 8;   // k offset (shorts)

    v4f acc[MI][4];
    #pragma unroll
    for (int a = 0; a < MI; ++a)
        #pragma unroll
        for (int b = 0; b < 4; ++b) acc[a][b] = (v4f){0.f, 0.f, 0.f, 0.f};

    for (int k0 = 0; k0 < d.K; k0 += 32) {
        __syncthreads();
        #pragma unroll
        for (int s = 0; s < NSEG / 4; ++s) {
            const int sg = wid * (NSEG / 4) + s;
            const unsigned short* src;
            int dst;
            if (sg < ASEG) {
                src = d.A + (i0 + sg * 16 + l4) * (long)d.lda + k0 + l2;
                dst = AH + sg * 512;
            } else if (sg < 2 * ASEG) {
                const int r = sg - ASEG;
                src = d.A + d.Apl + (i0 + r * 16 + l4) * (long)d.lda + k0 + l2;
                dst = AL + r * 512;
            } else if (sg < 2 * ASEG + 8) {
                const int r = sg - 2 * ASEG;
                src = d.W + (j0 + r * 16 + l4) * (long)d.ldw + k0 + l2;
                dst = WH + r * 512;
            } else {
                const int r = sg - 2 * ASEG - 8;
                src = d.W + d.Wpl + (j0 + r * 16 + l4) * (long)d.ldw + k0 + l2;
                dst = WL + r * 512;
            }
            glds16(src, &lds[dst]);
        }
        __syncthreads();

        v8bf af[MI], al[MI];
        #pragma unroll
        for (int mi = 0; mi < MI; ++mi) {
            const int aoff = (wm * (BM / 2) + mi * 16 + row16) * 32 + quad * 8;
            af[mi] = *(const v8bf*)&lds[AH + aoff];
            al[mi] = *(const v8bf*)&lds[AL + aoff];
        }
        #pragma unroll
        for (int nj = 0; nj < 4; ++nj) {
            const int boff = (wn * 64 + nj * 16 + row16) * 32 + quad * 8;
            v8bf bh = *(const v8bf*)&lds[WH + boff];
            v8bf bl = *(const v8bf*)&lds[WL + boff];
            #pragma unroll
            for (int mi = 0; mi < MI; ++mi) {
                acc[mi][nj] = __builtin_amdgcn_mfma_f32_16x16x32_bf16(af[mi], bh, acc[mi][nj], 0, 0, 0);
                acc[mi][nj] = __builtin_amdgcn_mfma_f32_16x16x32_bf16(af[mi], bl, acc[mi][nj], 0, 0, 0);
                acc[mi][nj] = __builtin_amdgcn_mfma_f32_16x16x32_bf16(al[mi], bh, acc[mi][nj], 0, 0, 0);
            }
        }
    }

    // C/D layout: col = lane&15 (W side), row = quad*4 + reg (A side)
    #pragma unroll
    for (int nj = 0; nj < 4; ++nj) {
        const int col = (int)j0 + wn * 64 + nj * 16 + row16;
        if (col < d.Nd) {
            const float bv = d.bias ? d.bias[col] : 0.f;
            #pragma unroll
            for (int mi = 0; mi < MI; ++mi) {
                #pragma unroll
                for (int r = 0; r < 4; ++r) {
                    const long row = i0 + wm * (BM / 2) + mi * 16 + quad * 4 + r;
                    const float v = acc[mi][nj][r] + bv;
                    if (d.mode == 0) {
                        d.C[row * (long)d.ldc + col] = v;
                    } else if (d.mode == 1) {
                        const long idx = row * (long)d.ldc + col;
                        const unsigned short hi = f2bf(v);
                        d.Cbf[idx] = hi; d.Cbf[idx + d.bfpl] = f2bf(v - bf2f(hi));
                    } else if (d.mode == 2) {
                        const long idx = row * (long)d.ldc + col;
                        d.C[idx] = v;
                        const unsigned short hi = f2bf(v);
                        d.Cbf[idx] = hi; d.Cbf[idx + d.bfpl] = f2bf(v - bf2f(hi));
                    } else {
                        const int srel = (int)(row / 3072);
                        const int rr = (int)row - srel * 3072;
                        const long orow = (long)(rr & 511) * MMAX + d.mbase + srel * 6 + (rr >> 9);
                        d.C[orow * 1024 + col] = v;
                    }
                }
            }
        }
    }
}

// =====================================================================
// fp32 -> bf16 hi/lo planes (weights), with zero-padding
// =====================================================================
__global__ void cvt_hilo(const float* __restrict__ x, int Ms, int Ks, int Kp,
                         unsigned short* __restrict__ y, long plane, int total)
{
    const int idx = blockIdx.x * 256 + threadIdx.x;
    if (idx >= total) return;
    const int row = idx / Kp;
    const int col = idx - row * Kp;
    const float v = (row < Ms && col < Ks) ? x[(long)row * Ks + col] : 0.f;
    const unsigned short hi = f2bf(v);
    y[idx] = hi;
    y[idx + plane] = f2bf(v - bf2f(hi));
}

// =====================================================================
// Triple RMSNorm: same row -> same rsqrt; writes 3 hi/lo outputs.
// =====================================================================
__global__ __launch_bounds__(256) void rmsnorm3_bf(
    const float* __restrict__ x,
    const float* __restrict__ w0, const float* __restrict__ w1,
    const float* __restrict__ w2,
    unsigned short* __restrict__ y0, unsigned short* __restrict__ y1,
    unsigned short* __restrict__ y2, long plane)
{
    const int r = blockIdx.x;
    const float* xr = x + (long)r * Dm;
    const int t = threadIdx.x;
    const float a = xr[t];
    const float b = xr[t + 256];
    float ss = a * a + b * b;
    #pragma unroll
    for (int off = 32; off > 0; off >>= 1) ss += __shfl_xor(ss, off, 64);
    __shared__ float w4[4];
    if ((t & 63) == 0) w4[t >> 6] = ss;
    __syncthreads();
    const float rs = rsqrtf((w4[0] + w4[1] + w4[2] + w4[3]) * (1.f / 512.f) + EPSR);
    const float na = a * rs, nb = b * rs;
    const long ia = (long)r * Dm + t, ib = ia + 256;
    unsigned short h;
    float v;
    v = na * w0[t];       h = f2bf(v); y0[ia] = h; y0[ia + plane] = f2bf(v - bf2f(h));
    v = nb * w0[t + 256]; h = f2bf(v); y0[ib] = h; y0[ib + plane] = f2bf(v - bf2f(h));
    v = na * w1[t];       h = f2bf(v); y1[ia] = h; y1[ia + plane] = f2bf(v - bf2f(h));
    v = nb * w1[t + 256]; h = f2bf(v); y1[ib] = h; y1[ib + plane] = f2bf(v - bf2f(h));
    v = na * w2[t];       h = f2bf(v); y2[ia] = h; y2[ia + plane] = f2bf(v - bf2f(h));
    v = nb * w2[t + 256]; h = f2bf(v); y2[ib] = h; y2[ib + plane] = f2bf(v - bf2f(h));
}

// =====================================================================
// GLU * exact GELU; h is [NT, 2816]-strided fp32 (cols >= 2730 unused);
// output bf16 hi/lo padded to KFF cols.
// =====================================================================
__global__ __launch_bounds__(256) void glu_gelu_bf(
    const float* __restrict__ h, unsigned short* __restrict__ y, long plane)
{
    const int r = blockIdx.x;
    const float* row = h + (long)r * NFF;
    for (int c = threadIdx.x; c < KFF; c += 256) {
        float v = 0.f;
        if (c < DFF) {
            const float sim = row[c];
            const float g = row[c + DFF];
            v = sim * (0.5f * g * (1.f + erff(g * 0.70710678118654752440f)));
        }
        const long idx = (long)r * KFF + c;
        const unsigned short hi = f2bf(v);
        y[idx] = hi;
        y[idx + plane] = f2bf(v - bf2f(hi));
    }
}

// =====================================================================
// Self-attention: grid = BBAT*NH*4 (4 query-chunks of 64), block 256.
// 4 threads per query, each owning a 16-dim slice. Output: bf16 hi/lo.
// =====================================================================
__global__ __launch_bounds__(256) void attn_self_kernel(
    const float* __restrict__ qb, const float* __restrict__ kvb,
    unsigned short* __restrict__ outbf, long plane)
{
    const int blk = blockIdx.x;
    const int qc = blk & 3;
    const int h = (blk >> 2) & 7;
    const int bat = blk >> 5;
    const int t = threadIdx.x;
    const int qi = t >> 2;
    const int ds = (t & 3) * 16;
    __shared__ float k_lds[64][DH];
    __shared__ float v_lds[64][DH];

    const long qrow = (long)(bat * Nn_ + qc * 64 + qi);
    const float* qp = qb + qrow * Dm + h * DH + ds;
    float q[16], o[16];
    #pragma unroll
    for (int d = 0; d < 16; d += 4) {
        const float4 v = *(const float4*)(qp + d);
        q[d] = v.x; q[d + 1] = v.y; q[d + 2] = v.z; q[d + 3] = v.w;
        o[d] = 0.f; o[d + 1] = 0.f; o[d + 2] = 0.f; o[d + 3] = 0.f;
    }
    float mx = -1e30f, l = 0.f;

    for (int jc = 0; jc < Nn_; jc += 64) {
        __syncthreads();
        {
            const int r = t >> 2;
            const int c = (t & 3) * 16;
            const float* kr = kvb + (long)(bat * Nn_ + jc + r) * 1024 + h * DH + c;
            #pragma unroll
            for (int cc = 0; cc < 16; cc += 4) {
                *(float4*)&k_lds[r][c + cc] = *(const float4*)(kr + cc);
                *(float4*)&v_lds[r][c + cc] = *(const float4*)(kr + 512 + cc);
            }
        }
        __syncthreads();
        for (int j = 0; j < 64; ++j) {
            float s = 0.f;
            #pragma unroll
            for (int d = 0; d < 16; ++d) s = fmaf(q[d], k_lds[j][ds + d], s);
            s += __shfl_xor(s, 1, 64);
            s += __shfl_xor(s, 2, 64);
            const float nm = fmaxf(mx, s);
            const float corr = __expf(mx - nm);
            const float p = __expf(s - nm);
            l = l * corr + p;
            #pragma unroll
            for (int d = 0; d < 16; ++d) o[d] = fmaf(p, v_lds[j][ds + d], o[d] * corr);
            mx = nm;
        }
    }
    const float inv = 1.f / l;
    const long obase = qrow * Dm + h * DH + ds;
    #pragma unroll
    for (int d = 0; d < 16; ++d) {
        const float v = o[d] * inv;
        const unsigned short hi = f2bf(v);
        outbf[obase + d] = hi;
        outbf[obase + d + plane] = f2bf(v - bf2f(hi));
    }
}

// =====================================================================
// Pooled attention, lane-per-m: block per (rb, head), 384 thr = 6 waves
// (one per query sharing rb). Phase 1: lane m computes score m via a
// 64-deep LDS dot (rows padded to 66 -> conflict-free b64). 12 shuffles
// for softmax. Phase 2: lane d accumulates O_d from broadcast p reads.
// =====================================================================
template <int M>
__global__ __launch_bounds__(384) void attn_pool_kernel(
    const float* __restrict__ qb, const float* __restrict__ kvc2,
    unsigned short* __restrict__ outbf, long plane)
{
    const int rb = blockIdx.x >> 3;
    const int h = blockIdx.x & 7;
    __shared__ float k_lds[M * 66];
    __shared__ float v_lds[M * 66];
    __shared__ float q_lds[6 * 64];
    __shared__ float p_lds[6 * 64];
    const int t = threadIdx.x;
    const int cb = rb >> 8, nn = rb & 255;

    for (int idx = t; idx < M * 64; idx += 384) {
        const int m = idx >> 6, d = idx & 63;
        const long base = ((long)rb * MMAX + m) * 1024 + h * DH + d;
        k_lds[m * 66 + d] = kvc2[base];
        v_lds[m * 66 + d] = kvc2[base + 512];
    }
    {   // exactly 384 query elements
        const int w = t >> 6, dd = t & 63;
        const long iq = (long)cb * 1536 + nn + w * 256;
        q_lds[t] = qb[iq * Dm + h * DH + dd];
    }
    __syncthreads();

    const int w = t >> 6;
    const int lane = t & 63;
    float s = -1e30f;
    if (lane < M) {
        s = 0.f;
        const float* kr = &k_lds[lane * 66];
        const float* qr = &q_lds[w * 64];
        #pragma unroll
        for (int dd = 0; dd < 64; dd += 2) {
            s = fmaf(qr[dd], kr[dd], s);
            s = fmaf(qr[dd + 1], kr[dd + 1], s);
        }
    }
    float mx = s;
    #pragma unroll
    for (int off = 32; off > 0; off >>= 1) mx = fmaxf(mx, __shfl_xor(mx, off, 64));
    const float p = __expf(s - mx);
    float l = p;
    #pragma unroll
    for (int off = 32; off > 0; off >>= 1) l += __shfl_xor(l, off, 64);
    p_lds[w * 64 + lane] = p / l;      // lanes >= M store 0

    float o = 0.f;
    const float* pr = &p_lds[w * 64];
    #pragma unroll
    for (int m = 0; m < M; ++m)
        o = fmaf(pr[m], v_lds[m * 66 + lane], o);

    const long iq = (long)cb * 1536 + nn + w * 256;
    const long oidx = iq * Dm + h * DH + lane;
    const unsigned short hi = f2bf(o);
    outbf[oidx] = hi;
    outbf[oidx + plane] = f2bf(o - bf2f(hi));
}

// =====================================================================
// Broadcast tokens [2,256,512] -> tokens fp32, tokbf hi/lo, msgs_bf set0
// =====================================================================
__global__ void replicate_kernel(const float* __restrict__ src,
                                 float* __restrict__ tokens,
                                 unsigned short* __restrict__ tokbf, long tpl,
                                 unsigned short* __restrict__ msg0, long mpl)
{
    const int idx = blockIdx.x * blockDim.x + threadIdx.x;
    if (idx >= NT * Dm) return;
    const float v = src[idx & (Bv * Nn_ * Dm - 1)];
    tokens[idx] = v;
    const unsigned short hi = f2bf(v);
    const unsigned short lo = f2bf(v - bf2f(hi));
    tokbf[idx] = hi; tokbf[idx + tpl] = lo;
    msg0[idx] = hi; msg0[idx + mpl] = lo;
}

// =====================================================================
extern "C" void kernel_launch(void* const* d_in, const int* in_sizes, int n_in,
                              void* d_out, int out_size, void* d_ws, size_t ws_size,
                              hipStream_t stream)
{
    const float* tok_in       = (const float*)d_in[0];
    const float* attn_norm_w  = (const float*)d_in[1];
    const float* attn_wq      = (const float*)d_in[2];
    const float* attn_wkv     = (const float*)d_in[3];
    const float* attn_wo      = (const float*)d_in[4];
    const float* ff_norm_w    = (const float*)d_in[5];
    const float* ff_keys_w    = (const float*)d_in[6];
    const float* ff_keys_b    = (const float*)d_in[7];
    const float* ff_values_w  = (const float*)d_in[8];
    const float* ff_values_b  = (const float*)d_in[9];
    const float* res_norm_w   = (const float*)d_in[10];
    const float* res_wq       = (const float*)d_in[11];
    const float* res_wkv      = (const float*)d_in[12];
    const float* res_wo       = (const float*)d_in[13];

    float* ws = (float*)d_ws;
    float* kvc2   = ws;                                  // 512*42*1024
    float* tokens = kvc2 + 512L * MMAX * 1024;           // NT*512
    float* qbuf   = tokens + (long)NT * Dm;              // NT*512
    float* kvbuf  = qbuf + (long)NT * Dm;                // NT*1024
    float* hbuf   = kvbuf + (long)NT * 1024;             // NT*2816

    unsigned short* us = (unsigned short*)(hbuf + (long)NT * NFF);
    const long apl = (long)NT * Dm;          // activation plane
    const long mpl = 7L * NT * Dm;           // msgs plane (7 sets)
    const long hpl = (long)NT * KFF;
    const long w1 = 512L * 512, w2 = 1024L * 512, w3 = (long)NFF * 512, w4 = 512L * KFF;
    unsigned short* msgs_bf = us; us += 2 * mpl;
    unsigned short* tokbf   = us; us += 2 * apl;
    unsigned short* xa      = us; us += 2 * apl;
    unsigned short* xf      = us; us += 2 * apl;
    unsigned short* xr      = us; us += 2 * apl;
    unsigned short* abf     = us; us += 2 * apl;
    unsigned short* hbf     = us; us += 2 * hpl;
    unsigned short* wqb  = us; us += 2 * w1;
    unsigned short* wkvb = us; us += 2 * w2;
    unsigned short* wob  = us; us += 2 * w1;
    unsigned short* fkb  = us; us += 2 * w3;
    unsigned short* fvb  = us; us += 2 * w4;
    unsigned short* rqb  = us; us += 2 * w1;
    unsigned short* rkvb = us; us += 2 * w2;
    unsigned short* rob  = us; us += 2 * w1;

    auto cvtw = [&](const float* src, int Ms, int Ks, int Kp, int Mpad,
                    unsigned short* dst, long pl) {
        const int tot = Mpad * Kp;
        cvt_hilo<<<(tot + 255) / 256, 256, 0, stream>>>(src, Ms, Ks, Kp, dst, pl, tot);
    };
    cvtw(attn_wq,     512,  512,  512, 512,  wqb,  w1);
    cvtw(attn_wkv,    1024, 512,  512, 1024, wkvb, w2);
    cvtw(attn_wo,     512,  512,  512, 512,  wob,  w1);
    cvtw(ff_keys_w,   DFF2, 512,  512, NFF,  fkb,  w3);
    cvtw(ff_values_w, 512,  DFF,  KFF, 512,  fvb,  w4);
    cvtw(res_wq,      512,  512,  512, 512,  rqb,  w1);
    cvtw(res_wkv,     1024, 512,  512, 1024, rkvb, w2);
    cvtw(res_wo,      512,  512,  512, 512,  rob,  w1);

    replicate_kernel<<<(NT * Dm + 255) / 256, 256, 0, stream>>>(
        tok_in, tokens, tokbf, apl, msgs_bf, mpl);

    auto mk = [](const unsigned short* A, long Apl, int lda,
                 const unsigned short* W, long Wpl, int ldw,
                 const float* bias, float* C, int ldc, int Nd,
                 unsigned short* Cbf, long bfpl, int mbase, int K,
                 int mode, int nbx) -> GDesc {
        GDesc d;
        d.A = A; d.Apl = Apl; d.lda = lda;
        d.W = W; d.Wpl = Wpl; d.ldw = ldw;
        d.bias = bias; d.C = C; d.ldc = ldc; d.Nd = Nd;
        d.Cbf = Cbf; d.bfpl = bfpl; d.mbase = mbase; d.K = K;
        d.mode = mode; d.nbx = nbx;
        return d;
    };

    for (int e = 0; e < 3; ++e) {
        rmsnorm3_bf<<<NT, 256, 0, stream>>>(tokens, attn_norm_w, ff_norm_w, res_norm_w,
                                            xa, xf, xr, apl);
        // ---- B1: wq + wkv + ffk (816 blocks) ----
        {
            GDesc dwq  = mk(xa,    apl, 512, wqb,  w1, 512, nullptr,   qbuf,  512,  512,  nullptr, 0, 0, 512, 0, 24);
            GDesc dwkv = mk(tokbf, apl, 512, wkvb, w2, 512, nullptr,   kvbuf, 1024, 1024, nullptr, 0, 0, 512, 0, 24);
            GDesc dffk = mk(xf,    apl, 512, fkb,  w3, 512, ff_keys_b, hbuf,  NFF,  DFF2, nullptr, 0, 0, 512, 0, 24);
            mega_gemm<128><<<816, 256, 0, stream>>>(dwq, dwkv, dffk, 96, 288);
        }
        attn_self_kernel<<<BBAT * NH * 4, 256, 0, stream>>>(qbuf, kvbuf, abf, apl);
        glu_gelu_bf<<<NT, 256, 0, stream>>>(hbuf, hbf, hpl);
        // ---- B2: wo + ffv (384 blocks, BM=64) ----
        {
            GDesc dwo  = mk(abf, apl, 512,  wob, w1, 512,  nullptr,     nullptr, 512, 512,
                            msgs_bf + (1 + 2 * e) * (long)NT * Dm, mpl, 0, 512, 1, 48);
            GDesc dffv = mk(hbf, hpl, KFF,  fvb, w4, KFF,  ff_values_b, nullptr, 512, 512,
                            msgs_bf + (2 + 2 * e) * (long)NT * Dm, mpl, 0, KFF, 1, 48);
            mega_gemm<64><<<384, 256, 0, stream>>>(dwo, dffv, dffv, 192, 384);
        }
        // ---- B3: rkv (remap) + rq ----
        {
            const int s0 = (e == 0) ? 0 : (1 + 2 * e);
            const int ns = (e == 0) ? 3 : 2;
            GDesc drkv = mk(msgs_bf + (long)s0 * NT * Dm, mpl, 512, rkvb, w2, 512,
                            nullptr, kvc2, 1024, 1024, nullptr, 0, s0 * 6, 512, 3, ns * 24);
            GDesc drq  = mk(xr, apl, 512, rqb, w1, 512, nullptr, qbuf, 512, 512,
                            nullptr, 0, 0, 512, 0, 24);
            const int nrkv = ns * 24 * 8;
            mega_gemm<128><<<nrkv + 96, 256, 0, stream>>>(drkv, drq, drq, nrkv, nrkv + 96);
        }
        // ---- pooled attention ----
        if (e == 0)      attn_pool_kernel<18><<<512 * NH, 384, 0, stream>>>(qbuf, kvc2, abf, apl);
        else if (e == 1) attn_pool_kernel<30><<<512 * NH, 384, 0, stream>>>(qbuf, kvc2, abf, apl);
        else             attn_pool_kernel<42><<<512 * NH, 384, 0, stream>>>(qbuf, kvc2, abf, apl);
        // ---- B4: ro ----
        {
            if (e < 2) {
                GDesc dro = mk(abf, apl, 512, rob, w1, 512, nullptr, tokens, 512, 512,
                               tokbf, apl, 0, 512, 2, 48);
                mega_gemm<64><<<192, 256, 0, stream>>>(dro, dro, dro, 192, 192);
            } else {
                GDesc dro = mk(abf, apl, 512, rob, w1, 512, nullptr, (float*)d_out, 512, 512,
                               nullptr, 0, 0, 512, 0, 48);
                mega_gemm<64><<<192, 256, 0, stream>>>(dro, dro, dro, 192, 192);
            }
        }
    }
}

// Round 6
// 1021.514 us; speedup vs baseline: 3.1327x; 1.0134x over previous
//
#include <hip/hip_runtime.h>
#include <math.h>

// ---- problem constants ----
#define Dm   512
#define Nn_  256
#define Bv   2
#define NBLK 6
#define BBAT 12            // NBLK*Bv
#define NT   3072          // BBAT*Nn_
#define NH   8
#define DH   64
#define DFF  1365
#define DFF2 2730
#define KFF  1408          // DFF padded to mult of 32 (ffv K)
#define NFF  2816          // DFF2 padded to mult of 128 (ffk N)
#define MMAX 42            // max pooled-context messages
#define EPSR 1.1920929e-07f

typedef _Float16 h16;
typedef h16  v8h  __attribute__((ext_vector_type(8)));
typedef float v4f __attribute__((ext_vector_type(4)));

__device__ inline h16 f2h(float v) { return (h16)v; }   // v_cvt_f16_f32, RNE

__device__ inline void glds16(const void* g, void* l) {
    __builtin_amdgcn_global_load_lds((const __attribute__((address_space(1))) void*)g,
                                     (__attribute__((address_space(3))) void*)l, 16, 0, 0);
}

// =====================================================================
// Multi-GEMM dispatcher, fp16 3-term compensated:
//   A = Ah + Al (fp16 planes, lo at +Apl); W = Wh + Wl (lo at +Wpl).
//   C[i,j] = sum_k A[i,k]*W[j,k] (+bias[j])
//   acc += Ah*Wh + Ah*Wl + Al*Wh   (drops only Al*Wl ~ 2^-24 rel)
// modes: 0 = fp32 C; 1 = fp16 hi/lo Cbf; 2 = both; 3 = fp32 pooled-ctx remap
// BM in {64,128}; BN = 128; K % 32 == 0.
// LDS tiles use XOR k-chunk swizzle (source-swizzled glds16 writes, reads
// at slot quad^(row&3)) to spread fragment reads across 4 bank groups.
// =====================================================================
struct GDesc {
    const h16* A;
    const h16* W;
    const float* bias;
    float* C;
    h16* Cbf;
    long Apl, Wpl, bfpl;
    int lda, ldw, ldc, Nd, mbase, K, mode, nbx;
};

template <int BM>
__global__ __launch_bounds__(256) void mega_gemm(GDesc d0, GDesc d1, GDesc d2,
                                                 int n0, int n01)
{
    constexpr int MI = BM / 32;          // 16-row acc tiles per wave (m dir)
    constexpr int ASEG = BM / 16;        // 16-row segments per A plane
    constexpr int NSEG = 2 * ASEG + 16;  // staging segments (Ah,Al,Wh,Wl)
    constexpr int AH = 0, AL = BM * 32, WH = 2 * BM * 32, WL = 2 * BM * 32 + 4096;
    __shared__ h16 lds[2 * BM * 32 + 2 * 4096];

    GDesc d; int lb = blockIdx.x;
    if (lb < n0) d = d0;
    else if (lb < n01) { d = d1; lb -= n0; }
    else { d = d2; lb -= n01; }
    const int bx = lb % d.nbx;
    const int by = lb / d.nbx;

    const int tid = threadIdx.x;
    const int wid = tid >> 6;
    const int lane = tid & 63;
    const int wm = wid >> 1, wn = wid & 1;
    const int row16 = lane & 15, quad = lane >> 4;
    const long i0 = (long)bx * BM;
    const long j0 = (long)by * 128;
    const int l4 = lane >> 2;                      // row within 16-row segment
    const int l2s = ((lane & 3) ^ (l4 & 3)) * 8;   // swizzled k-chunk src offset
    const int ksw = (quad ^ (row16 & 3)) * 8;      // swizzled fragment slot

    v4f acc[MI][4];
    #pragma unroll
    for (int a = 0; a < MI; ++a)
        #pragma unroll
        for (int b = 0; b < 4; ++b) acc[a][b] = (v4f){0.f, 0.f, 0.f, 0.f};

    for (int k0 = 0; k0 < d.K; k0 += 32) {
        __syncthreads();
        #pragma unroll
        for (int s = 0; s < NSEG / 4; ++s) {
            const int sg = wid * (NSEG / 4) + s;
            const h16* src;
            int dst;
            if (sg < ASEG) {
                src = d.A + (i0 + sg * 16 + l4) * (long)d.lda + k0 + l2s;
                dst = AH + sg * 512;
            } else if (sg < 2 * ASEG) {
                const int r = sg - ASEG;
                src = d.A + d.Apl + (i0 + r * 16 + l4) * (long)d.lda + k0 + l2s;
                dst = AL + r * 512;
            } else if (sg < 2 * ASEG + 8) {
                const int r = sg - 2 * ASEG;
                src = d.W + (j0 + r * 16 + l4) * (long)d.ldw + k0 + l2s;
                dst = WH + r * 512;
            } else {
                const int r = sg - 2 * ASEG - 8;
                src = d.W + d.Wpl + (j0 + r * 16 + l4) * (long)d.ldw + k0 + l2s;
                dst = WL + r * 512;
            }
            glds16(src, &lds[dst]);
        }
        __syncthreads();

        v8h af[MI], al[MI];
        #pragma unroll
        for (int mi = 0; mi < MI; ++mi) {
            const int aoff = (wm * (BM / 2) + mi * 16 + row16) * 32 + ksw;
            af[mi] = *(const v8h*)&lds[AH + aoff];
            al[mi] = *(const v8h*)&lds[AL + aoff];
        }
        #pragma unroll
        for (int nj = 0; nj < 4; ++nj) {
            const int boff = (wn * 64 + nj * 16 + row16) * 32 + ksw;
            v8h bh = *(const v8h*)&lds[WH + boff];
            v8h bl = *(const v8h*)&lds[WL + boff];
            #pragma unroll
            for (int mi = 0; mi < MI; ++mi) {
                acc[mi][nj] = __builtin_amdgcn_mfma_f32_16x16x32_f16(af[mi], bh, acc[mi][nj], 0, 0, 0);
                acc[mi][nj] = __builtin_amdgcn_mfma_f32_16x16x32_f16(af[mi], bl, acc[mi][nj], 0, 0, 0);
                acc[mi][nj] = __builtin_amdgcn_mfma_f32_16x16x32_f16(al[mi], bh, acc[mi][nj], 0, 0, 0);
            }
        }
    }

    // C/D layout: col = lane&15 (W side), row = quad*4 + reg (A side)
    #pragma unroll
    for (int nj = 0; nj < 4; ++nj) {
        const int col = (int)j0 + wn * 64 + nj * 16 + row16;
        if (col < d.Nd) {
            const float bv = d.bias ? d.bias[col] : 0.f;
            #pragma unroll
            for (int mi = 0; mi < MI; ++mi) {
                #pragma unroll
                for (int r = 0; r < 4; ++r) {
                    const long row = i0 + wm * (BM / 2) + mi * 16 + quad * 4 + r;
                    const float v = acc[mi][nj][r] + bv;
                    if (d.mode == 0) {
                        d.C[row * (long)d.ldc + col] = v;
                    } else if (d.mode == 1) {
                        const long idx = row * (long)d.ldc + col;
                        const h16 hi = f2h(v);
                        d.Cbf[idx] = hi; d.Cbf[idx + d.bfpl] = f2h(v - (float)hi);
                    } else if (d.mode == 2) {
                        const long idx = row * (long)d.ldc + col;
                        d.C[idx] = v;
                        const h16 hi = f2h(v);
                        d.Cbf[idx] = hi; d.Cbf[idx + d.bfpl] = f2h(v - (float)hi);
                    } else {
                        const int srel = (int)(row / 3072);
                        const int rr = (int)row - srel * 3072;
                        const long orow = (long)(rr & 511) * MMAX + d.mbase + srel * 6 + (rr >> 9);
                        d.C[orow * 1024 + col] = v;
                    }
                }
            }
        }
    }
}

// =====================================================================
// fp32 -> fp16 hi/lo planes, with zero-padding
// =====================================================================
__global__ void cvt_hilo(const float* __restrict__ x, int Ms, int Ks, int Kp,
                         h16* __restrict__ y, long plane, int total)
{
    const int idx = blockIdx.x * 256 + threadIdx.x;
    if (idx >= total) return;
    const int row = idx / Kp;
    const int col = idx - row * Kp;
    const float v = (row < Ms && col < Ks) ? x[(long)row * Ks + col] : 0.f;
    const h16 hi = f2h(v);
    y[idx] = hi;
    y[idx + plane] = f2h(v - (float)hi);
}

// =====================================================================
// Triple RMSNorm: same row -> same rsqrt; writes 3 fp16 hi/lo outputs.
// =====================================================================
__global__ __launch_bounds__(256) void rmsnorm3_bf(
    const float* __restrict__ x,
    const float* __restrict__ w0, const float* __restrict__ w1,
    const float* __restrict__ w2,
    h16* __restrict__ y0, h16* __restrict__ y1,
    h16* __restrict__ y2, long plane)
{
    const int r = blockIdx.x;
    const float* xr = x + (long)r * Dm;
    const int t = threadIdx.x;
    const float a = xr[t];
    const float b = xr[t + 256];
    float ss = a * a + b * b;
    #pragma unroll
    for (int off = 32; off > 0; off >>= 1) ss += __shfl_xor(ss, off, 64);
    __shared__ float w4[4];
    if ((t & 63) == 0) w4[t >> 6] = ss;
    __syncthreads();
    const float rs = rsqrtf((w4[0] + w4[1] + w4[2] + w4[3]) * (1.f / 512.f) + EPSR);
    const float na = a * rs, nb = b * rs;
    const long ia = (long)r * Dm + t, ib = ia + 256;
    h16 h;
    float v;
    v = na * w0[t];       h = f2h(v); y0[ia] = h; y0[ia + plane] = f2h(v - (float)h);
    v = nb * w0[t + 256]; h = f2h(v); y0[ib] = h; y0[ib + plane] = f2h(v - (float)h);
    v = na * w1[t];       h = f2h(v); y1[ia] = h; y1[ia + plane] = f2h(v - (float)h);
    v = nb * w1[t + 256]; h = f2h(v); y1[ib] = h; y1[ib + plane] = f2h(v - (float)h);
    v = na * w2[t];       h = f2h(v); y2[ia] = h; y2[ia + plane] = f2h(v - (float)h);
    v = nb * w2[t + 256]; h = f2h(v); y2[ib] = h; y2[ib + plane] = f2h(v - (float)h);
}

// =====================================================================
// GLU * exact GELU; h is [NT, 2816]-strided fp32; output fp16 hi/lo, KFF cols.
// =====================================================================
__global__ __launch_bounds__(256) void glu_gelu_bf(
    const float* __restrict__ h, h16* __restrict__ y, long plane)
{
    const int r = blockIdx.x;
    const float* row = h + (long)r * NFF;
    for (int c = threadIdx.x; c < KFF; c += 256) {
        float v = 0.f;
        if (c < DFF) {
            const float sim = row[c];
            const float g = row[c + DFF];
            v = sim * (0.5f * g * (1.f + erff(g * 0.70710678118654752440f)));
        }
        const long idx = (long)r * KFF + c;
        const h16 hi = f2h(v);
        y[idx] = hi;
        y[idx + plane] = f2h(v - (float)hi);
    }
}

// =====================================================================
// Self-attention: grid = BBAT*NH*4 (4 query-chunks of 64), block 256.
// 4 threads per query, each owning a 16-dim slice. Output: fp16 hi/lo.
// =====================================================================
__global__ __launch_bounds__(256) void attn_self_kernel(
    const float* __restrict__ qb, const float* __restrict__ kvb,
    h16* __restrict__ outbf, long plane)
{
    const int blk = blockIdx.x;
    const int qc = blk & 3;
    const int h = (blk >> 2) & 7;
    const int bat = blk >> 5;
    const int t = threadIdx.x;
    const int qi = t >> 2;
    const int ds = (t & 3) * 16;
    __shared__ float k_lds[64][DH];
    __shared__ float v_lds[64][DH];

    const long qrow = (long)(bat * Nn_ + qc * 64 + qi);
    const float* qp = qb + qrow * Dm + h * DH + ds;
    float q[16], o[16];
    #pragma unroll
    for (int d = 0; d < 16; d += 4) {
        const float4 v = *(const float4*)(qp + d);
        q[d] = v.x; q[d + 1] = v.y; q[d + 2] = v.z; q[d + 3] = v.w;
        o[d] = 0.f; o[d + 1] = 0.f; o[d + 2] = 0.f; o[d + 3] = 0.f;
    }
    float mx = -1e30f, l = 0.f;

    for (int jc = 0; jc < Nn_; jc += 64) {
        __syncthreads();
        {
            const int r = t >> 2;
            const int c = (t & 3) * 16;
            const float* kr = kvb + (long)(bat * Nn_ + jc + r) * 1024 + h * DH + c;
            #pragma unroll
            for (int cc = 0; cc < 16; cc += 4) {
                *(float4*)&k_lds[r][c + cc] = *(const float4*)(kr + cc);
                *(float4*)&v_lds[r][c + cc] = *(const float4*)(kr + 512 + cc);
            }
        }
        __syncthreads();
        for (int j = 0; j < 64; ++j) {
            float s = 0.f;
            #pragma unroll
            for (int d = 0; d < 16; ++d) s = fmaf(q[d], k_lds[j][ds + d], s);
            s += __shfl_xor(s, 1, 64);
            s += __shfl_xor(s, 2, 64);
            const float nm = fmaxf(mx, s);
            const float corr = __expf(mx - nm);
            const float p = __expf(s - nm);
            l = l * corr + p;
            #pragma unroll
            for (int d = 0; d < 16; ++d) o[d] = fmaf(p, v_lds[j][ds + d], o[d] * corr);
            mx = nm;
        }
    }
    const float inv = 1.f / l;
    const long obase = qrow * Dm + h * DH + ds;
    #pragma unroll
    for (int d = 0; d < 16; ++d) {
        const float v = o[d] * inv;
        const h16 hi = f2h(v);
        outbf[obase + d] = hi;
        outbf[obase + d + plane] = f2h(v - (float)hi);
    }
}

// =====================================================================
// Pooled attention, lane-per-m: block per (rb, head), 384 thr = 6 waves.
// =====================================================================
template <int M>
__global__ __launch_bounds__(384) void attn_pool_kernel(
    const float* __restrict__ qb, const float* __restrict__ kvc2,
    h16* __restrict__ outbf, long plane)
{
    const int rb = blockIdx.x >> 3;
    const int h = blockIdx.x & 7;
    __shared__ float k_lds[M * 66];
    __shared__ float v_lds[M * 66];
    __shared__ float q_lds[6 * 64];
    __shared__ float p_lds[6 * 64];
    const int t = threadIdx.x;
    const int cb = rb >> 8, nn = rb & 255;

    for (int idx = t; idx < M * 64; idx += 384) {
        const int m = idx >> 6, d = idx & 63;
        const long base = ((long)rb * MMAX + m) * 1024 + h * DH + d;
        k_lds[m * 66 + d] = kvc2[base];
        v_lds[m * 66 + d] = kvc2[base + 512];
    }
    {
        const int w = t >> 6, dd = t & 63;
        const long iq = (long)cb * 1536 + nn + w * 256;
        q_lds[t] = qb[iq * Dm + h * DH + dd];
    }
    __syncthreads();

    const int w = t >> 6;
    const int lane = t & 63;
    float s = -1e30f;
    if (lane < M) {
        s = 0.f;
        const float* kr = &k_lds[lane * 66];
        const float* qr = &q_lds[w * 64];
        #pragma unroll
        for (int dd = 0; dd < 64; dd += 2) {
            s = fmaf(qr[dd], kr[dd], s);
            s = fmaf(qr[dd + 1], kr[dd + 1], s);
        }
    }
    float mx = s;
    #pragma unroll
    for (int off = 32; off > 0; off >>= 1) mx = fmaxf(mx, __shfl_xor(mx, off, 64));
    const float p = __expf(s - mx);
    float l = p;
    #pragma unroll
    for (int off = 32; off > 0; off >>= 1) l += __shfl_xor(l, off, 64);
    p_lds[w * 64 + lane] = p / l;

    float o = 0.f;
    const float* pr = &p_lds[w * 64];
    #pragma unroll
    for (int m = 0; m < M; ++m)
        o = fmaf(pr[m], v_lds[m * 66 + lane], o);

    const long iq = (long)cb * 1536 + nn + w * 256;
    const long oidx = iq * Dm + h * DH + lane;
    const h16 hi = f2h(o);
    outbf[oidx] = hi;
    outbf[oidx + plane] = f2h(o - (float)hi);
}

// =====================================================================
// Broadcast tokens [2,256,512] -> tokens fp32, tokbf hi/lo, msgs set0
// =====================================================================
__global__ void replicate_kernel(const float* __restrict__ src,
                                 float* __restrict__ tokens,
                                 h16* __restrict__ tokbf, long tpl,
                                 h16* __restrict__ msg0, long mpl)
{
    const int idx = blockIdx.x * blockDim.x + threadIdx.x;
    if (idx >= NT * Dm) return;
    const float v = src[idx & (Bv * Nn_ * Dm - 1)];
    tokens[idx] = v;
    const h16 hi = f2h(v);
    const h16 lo = f2h(v - (float)hi);
    tokbf[idx] = hi; tokbf[idx + tpl] = lo;
    msg0[idx] = hi; msg0[idx + mpl] = lo;
}

// =====================================================================
extern "C" void kernel_launch(void* const* d_in, const int* in_sizes, int n_in,
                              void* d_out, int out_size, void* d_ws, size_t ws_size,
                              hipStream_t stream)
{
    const float* tok_in       = (const float*)d_in[0];
    const float* attn_norm_w  = (const float*)d_in[1];
    const float* attn_wq      = (const float*)d_in[2];
    const float* attn_wkv     = (const float*)d_in[3];
    const float* attn_wo      = (const float*)d_in[4];
    const float* ff_norm_w    = (const float*)d_in[5];
    const float* ff_keys_w    = (const float*)d_in[6];
    const float* ff_keys_b    = (const float*)d_in[7];
    const float* ff_values_w  = (const float*)d_in[8];
    const float* ff_values_b  = (const float*)d_in[9];
    const float* res_norm_w   = (const float*)d_in[10];
    const float* res_wq       = (const float*)d_in[11];
    const float* res_wkv      = (const float*)d_in[12];
    const float* res_wo       = (const float*)d_in[13];

    float* ws = (float*)d_ws;
    float* kvc2   = ws;                                  // 512*42*1024
    float* tokens = kvc2 + 512L * MMAX * 1024;           // NT*512
    float* qbuf   = tokens + (long)NT * Dm;              // NT*512
    float* kvbuf  = qbuf + (long)NT * Dm;                // NT*1024
    float* hbuf   = kvbuf + (long)NT * 1024;             // NT*2816

    h16* us = (h16*)(hbuf + (long)NT * NFF);
    const long apl = (long)NT * Dm;          // activation plane
    const long mpl = 7L * NT * Dm;           // msgs plane (7 sets)
    const long hpl = (long)NT * KFF;
    const long w1 = 512L * 512, w2 = 1024L * 512, w3 = (long)NFF * 512, w4 = 512L * KFF;
    h16* msgs_bf = us; us += 2 * mpl;
    h16* tokbf   = us; us += 2 * apl;
    h16* xa      = us; us += 2 * apl;
    h16* xf      = us; us += 2 * apl;
    h16* xr      = us; us += 2 * apl;
    h16* abf     = us; us += 2 * apl;
    h16* hbf     = us; us += 2 * hpl;
    h16* wqb  = us; us += 2 * w1;
    h16* wkvb = us; us += 2 * w2;
    h16* wob  = us; us += 2 * w1;
    h16* fkb  = us; us += 2 * w3;
    h16* fvb  = us; us += 2 * w4;
    h16* rqb  = us; us += 2 * w1;
    h16* rkvb = us; us += 2 * w2;
    h16* rob  = us; us += 2 * w1;

    auto cvtw = [&](const float* src, int Ms, int Ks, int Kp, int Mpad,
                    h16* dst, long pl) {
        const int tot = Mpad * Kp;
        cvt_hilo<<<(tot + 255) / 256, 256, 0, stream>>>(src, Ms, Ks, Kp, dst, pl, tot);
    };
    cvtw(attn_wq,     512,  512,  512, 512,  wqb,  w1);
    cvtw(attn_wkv,    1024, 512,  512, 1024, wkvb, w2);
    cvtw(attn_wo,     512,  512,  512, 512,  wob,  w1);
    cvtw(ff_keys_w,   DFF2, 512,  512, NFF,  fkb,  w3);
    cvtw(ff_values_w, 512,  DFF,  KFF, 512,  fvb,  w4);
    cvtw(res_wq,      512,  512,  512, 512,  rqb,  w1);
    cvtw(res_wkv,     1024, 512,  512, 1024, rkvb, w2);
    cvtw(res_wo,      512,  512,  512, 512,  rob,  w1);

    replicate_kernel<<<(NT * Dm + 255) / 256, 256, 0, stream>>>(
        tok_in, tokens, tokbf, apl, msgs_bf, mpl);

    auto mk = [](const h16* A, long Apl, int lda,
                 const h16* W, long Wpl, int ldw,
                 const float* bias, float* C, int ldc, int Nd,
                 h16* Cbf, long bfpl, int mbase, int K,
                 int mode, int nbx) -> GDesc {
        GDesc d;
        d.A = A; d.Apl = Apl; d.lda = lda;
        d.W = W; d.Wpl = Wpl; d.ldw = ldw;
        d.bias = bias; d.C = C; d.ldc = ldc; d.Nd = Nd;
        d.Cbf = Cbf; d.bfpl = bfpl; d.mbase = mbase; d.K = K;
        d.mode = mode; d.nbx = nbx;
        return d;
    };

    for (int e = 0; e < 3; ++e) {
        rmsnorm3_bf<<<NT, 256, 0, stream>>>(tokens, attn_norm_w, ff_norm_w, res_norm_w,
                                            xa, xf, xr, apl);
        // ---- B1: wq + wkv + ffk (816 blocks) ----
        {
            GDesc dwq  = mk(xa,    apl, 512, wqb,  w1, 512, nullptr,   qbuf,  512,  512,  nullptr, 0, 0, 512, 0, 24);
            GDesc dwkv = mk(tokbf, apl, 512, wkvb, w2, 512, nullptr,   kvbuf, 1024, 1024, nullptr, 0, 0, 512, 0, 24);
            GDesc dffk = mk(xf,    apl, 512, fkb,  w3, 512, ff_keys_b, hbuf,  NFF,  DFF2, nullptr, 0, 0, 512, 0, 24);
            mega_gemm<128><<<816, 256, 0, stream>>>(dwq, dwkv, dffk, 96, 288);
        }
        attn_self_kernel<<<BBAT * NH * 4, 256, 0, stream>>>(qbuf, kvbuf, abf, apl);
        glu_gelu_bf<<<NT, 256, 0, stream>>>(hbuf, hbf, hpl);
        // ---- B2: wo + ffv (384 blocks, BM=64) ----
        {
            GDesc dwo  = mk(abf, apl, 512,  wob, w1, 512,  nullptr,     nullptr, 512, 512,
                            msgs_bf + (1 + 2 * e) * (long)NT * Dm, mpl, 0, 512, 1, 48);
            GDesc dffv = mk(hbf, hpl, KFF,  fvb, w4, KFF,  ff_values_b, nullptr, 512, 512,
                            msgs_bf + (2 + 2 * e) * (long)NT * Dm, mpl, 0, KFF, 1, 48);
            mega_gemm<64><<<384, 256, 0, stream>>>(dwo, dffv, dffv, 192, 384);
        }
        // ---- B3: rkv (remap) + rq ----
        {
            const int s0 = (e == 0) ? 0 : (1 + 2 * e);
            const int ns = (e == 0) ? 3 : 2;
            GDesc drkv = mk(msgs_bf + (long)s0 * NT * Dm, mpl, 512, rkvb, w2, 512,
                            nullptr, kvc2, 1024, 1024, nullptr, 0, s0 * 6, 512, 3, ns * 24);
            GDesc drq  = mk(xr, apl, 512, rqb, w1, 512, nullptr, qbuf, 512, 512,
                            nullptr, 0, 0, 512, 0, 24);
            const int nrkv = ns * 24 * 8;
            mega_gemm<128><<<nrkv + 96, 256, 0, stream>>>(drkv, drq, drq, nrkv, nrkv + 96);
        }
        // ---- pooled attention ----
        if (e == 0)      attn_pool_kernel<18><<<512 * NH, 384, 0, stream>>>(qbuf, kvc2, abf, apl);
        else if (e == 1) attn_pool_kernel<30><<<512 * NH, 384, 0, stream>>>(qbuf, kvc2, abf, apl);
        else             attn_pool_kernel<42><<<512 * NH, 384, 0, stream>>>(qbuf, kvc2, abf, apl);
        // ---- B4: ro ----
        {
            if (e < 2) {
                GDesc dro = mk(abf, apl, 512, rob, w1, 512, nullptr, tokens, 512, 512,
                               tokbf, apl, 0, 512, 2, 48);
                mega_gemm<64><<<192, 256, 0, stream>>>(dro, dro, dro, 192, 192);
            } else {
                GDesc dro = mk(abf, apl, 512, rob, w1, 512, nullptr, (float*)d_out, 512, 512,
                               nullptr, 0, 0, 512, 0, 48);
                mega_gemm<64><<<192, 256, 0, stream>>>(dro, dro, dro, 192, 192);
            }
        }
    }
}

// Round 7
// 940.237 us; speedup vs baseline: 3.4035x; 1.0864x over previous
//
#include <hip/hip_runtime.h>
#include <math.h>

// ---- problem constants ----
#define Dm   512
#define Nn_  256
#define Bv   2
#define NBLK 6
#define BBAT 12            // NBLK*Bv
#define NT   3072          // BBAT*Nn_
#define NH   8
#define DH   64
#define DFF  1365
#define DFF2 2730
#define KFF  1408          // DFF padded to mult of 32 (ffv K)
#define NFF  2816          // DFF2 padded to mult of 128 (ffk N)
#define MMAX 42            // max pooled-context messages
#define EPSR 1.1920929e-07f

typedef _Float16 h16;
typedef h16  v8h  __attribute__((ext_vector_type(8)));
typedef float v4f __attribute__((ext_vector_type(4)));

__device__ inline h16 f2h(float v) { return (h16)v; }   // v_cvt_f16_f32, RNE

__device__ inline void glds16(const void* g, void* l) {
    __builtin_amdgcn_global_load_lds((const __attribute__((address_space(1))) void*)g,
                                     (__attribute__((address_space(3))) void*)l, 16, 0, 0);
}

// =====================================================================
// Multi-GEMM dispatcher, fp16 3-term compensated, DOUBLE-BUFFERED LDS:
//   A = Ah + Al (fp16 planes, lo at +Apl); W = Wh + Wl (lo at +Wpl).
//   C[i,j] = sum_k A[i,k]*W[j,k] (+bias[j])
//   acc += Ah*Wh + Ah*Wl + Al*Wh   (drops only Al*Wl ~ 2^-24 rel)
// Pipeline: one __syncthreads per k-iter; stage(k+1) issued right after
// the barrier so the vmcnt(0) drain at the NEXT barrier waits on loads
// that have been in flight for a full compute phase (~600 cyc) -> hidden.
// modes: 0 = fp32 C; 1 = fp16 hi/lo Cbf; 2 = both; 3 = fp32 pooled-ctx remap
// BM in {64,128}; BN = 128; K % 32 == 0.
// =====================================================================
struct GDesc {
    const h16* A;
    const h16* W;
    const float* bias;
    float* C;
    h16* Cbf;
    long Apl, Wpl, bfpl;
    int lda, ldw, ldc, Nd, mbase, K, mode, nbx;
};

template <int BM>
__global__ __launch_bounds__(256) void mega_gemm(GDesc d0, GDesc d1, GDesc d2,
                                                 int n0, int n01)
{
    constexpr int MI = BM / 32;          // 16-row acc tiles per wave (m dir)
    constexpr int ASEG = BM / 16;        // 16-row segments per A plane
    constexpr int NSEG = 2 * ASEG + 16;  // staging segments (Ah,Al,Wh,Wl)
    constexpr int BUF = 2 * BM * 32 + 2 * 4096;   // h16 per buffer
    constexpr int AH = 0, AL = BM * 32, WH = 2 * BM * 32, WL = 2 * BM * 32 + 4096;
    __shared__ h16 lds[2 * BUF];

    GDesc d; int lb = blockIdx.x;
    if (lb < n0) d = d0;
    else if (lb < n01) { d = d1; lb -= n0; }
    else { d = d2; lb -= n01; }
    const int bx = lb % d.nbx;
    const int by = lb / d.nbx;

    const int tid = threadIdx.x;
    const int wid = tid >> 6;
    const int lane = tid & 63;
    const int wm = wid >> 1, wn = wid & 1;
    const int row16 = lane & 15, quad = lane >> 4;
    const long i0 = (long)bx * BM;
    const long j0 = (long)by * 128;
    const int l4 = lane >> 2;                      // row within 16-row segment
    const int l2s = ((lane & 3) ^ (l4 & 3)) * 8;   // swizzled k-chunk src offset
    const int ksw = (quad ^ (row16 & 3)) * 8;      // matching fragment slot

    auto stage = [&](int k0, h16* buf) {
        #pragma unroll
        for (int s = 0; s < NSEG / 4; ++s) {
            const int sg = wid * (NSEG / 4) + s;
            const h16* src;
            int dst;
            if (sg < ASEG) {
                src = d.A + (i0 + sg * 16 + l4) * (long)d.lda + k0 + l2s;
                dst = AH + sg * 512;
            } else if (sg < 2 * ASEG) {
                const int r = sg - ASEG;
                src = d.A + d.Apl + (i0 + r * 16 + l4) * (long)d.lda + k0 + l2s;
                dst = AL + r * 512;
            } else if (sg < 2 * ASEG + 8) {
                const int r = sg - 2 * ASEG;
                src = d.W + (j0 + r * 16 + l4) * (long)d.ldw + k0 + l2s;
                dst = WH + r * 512;
            } else {
                const int r = sg - 2 * ASEG - 8;
                src = d.W + d.Wpl + (j0 + r * 16 + l4) * (long)d.ldw + k0 + l2s;
                dst = WL + r * 512;
            }
            glds16(src, &buf[dst]);
        }
    };

    v4f acc[MI][4];
    #pragma unroll
    for (int a = 0; a < MI; ++a)
        #pragma unroll
        for (int b = 0; b < 4; ++b) acc[a][b] = (v4f){0.f, 0.f, 0.f, 0.f};

    stage(0, lds);
    int cur = 0;
    for (int k0 = 0; k0 < d.K; k0 += 32) {
        __syncthreads();   // drains stage(k0) (in flight one full iter) + frees alt buffer
        h16* cbuf = &lds[cur * BUF];
        if (k0 + 32 < d.K) stage(k0 + 32, &lds[(cur ^ 1) * BUF]);

        v8h af[MI], al[MI];
        #pragma unroll
        for (int mi = 0; mi < MI; ++mi) {
            const int aoff = (wm * (BM / 2) + mi * 16 + row16) * 32 + ksw;
            af[mi] = *(const v8h*)&cbuf[AH + aoff];
            al[mi] = *(const v8h*)&cbuf[AL + aoff];
        }
        #pragma unroll
        for (int nj = 0; nj < 4; ++nj) {
            const int boff = (wn * 64 + nj * 16 + row16) * 32 + ksw;
            v8h bh = *(const v8h*)&cbuf[WH + boff];
            v8h bl = *(const v8h*)&cbuf[WL + boff];
            #pragma unroll
            for (int mi = 0; mi < MI; ++mi) {
                acc[mi][nj] = __builtin_amdgcn_mfma_f32_16x16x32_f16(af[mi], bh, acc[mi][nj], 0, 0, 0);
                acc[mi][nj] = __builtin_amdgcn_mfma_f32_16x16x32_f16(af[mi], bl, acc[mi][nj], 0, 0, 0);
                acc[mi][nj] = __builtin_amdgcn_mfma_f32_16x16x32_f16(al[mi], bh, acc[mi][nj], 0, 0, 0);
            }
        }
        cur ^= 1;
    }

    // C/D layout: col = lane&15 (W side), row = quad*4 + reg (A side)
    #pragma unroll
    for (int nj = 0; nj < 4; ++nj) {
        const int col = (int)j0 + wn * 64 + nj * 16 + row16;
        if (col < d.Nd) {
            const float bv = d.bias ? d.bias[col] : 0.f;
            #pragma unroll
            for (int mi = 0; mi < MI; ++mi) {
                #pragma unroll
                for (int r = 0; r < 4; ++r) {
                    const long row = i0 + wm * (BM / 2) + mi * 16 + quad * 4 + r;
                    const float v = acc[mi][nj][r] + bv;
                    if (d.mode == 0) {
                        d.C[row * (long)d.ldc + col] = v;
                    } else if (d.mode == 1) {
                        const long idx = row * (long)d.ldc + col;
                        const h16 hi = f2h(v);
                        d.Cbf[idx] = hi; d.Cbf[idx + d.bfpl] = f2h(v - (float)hi);
                    } else if (d.mode == 2) {
                        const long idx = row * (long)d.ldc + col;
                        d.C[idx] = v;
                        const h16 hi = f2h(v);
                        d.Cbf[idx] = hi; d.Cbf[idx + d.bfpl] = f2h(v - (float)hi);
                    } else {
                        const int srel = (int)(row / 3072);
                        const int rr = (int)row - srel * 3072;
                        const long orow = (long)(rr & 511) * MMAX + d.mbase + srel * 6 + (rr >> 9);
                        d.C[orow * 1024 + col] = v;
                    }
                }
            }
        }
    }
}

// =====================================================================
// fp32 -> fp16 hi/lo planes, with zero-padding
// =====================================================================
__global__ void cvt_hilo(const float* __restrict__ x, int Ms, int Ks, int Kp,
                         h16* __restrict__ y, long plane, int total)
{
    const int idx = blockIdx.x * 256 + threadIdx.x;
    if (idx >= total) return;
    const int row = idx / Kp;
    const int col = idx - row * Kp;
    const float v = (row < Ms && col < Ks) ? x[(long)row * Ks + col] : 0.f;
    const h16 hi = f2h(v);
    y[idx] = hi;
    y[idx + plane] = f2h(v - (float)hi);
}

// =====================================================================
// Triple RMSNorm: same row -> same rsqrt; writes 3 fp16 hi/lo outputs.
// =====================================================================
__global__ __launch_bounds__(256) void rmsnorm3_bf(
    const float* __restrict__ x,
    const float* __restrict__ w0, const float* __restrict__ w1,
    const float* __restrict__ w2,
    h16* __restrict__ y0, h16* __restrict__ y1,
    h16* __restrict__ y2, long plane)
{
    const int r = blockIdx.x;
    const float* xr = x + (long)r * Dm;
    const int t = threadIdx.x;
    const float a = xr[t];
    const float b = xr[t + 256];
    float ss = a * a + b * b;
    #pragma unroll
    for (int off = 32; off > 0; off >>= 1) ss += __shfl_xor(ss, off, 64);
    __shared__ float w4[4];
    if ((t & 63) == 0) w4[t >> 6] = ss;
    __syncthreads();
    const float rs = rsqrtf((w4[0] + w4[1] + w4[2] + w4[3]) * (1.f / 512.f) + EPSR);
    const float na = a * rs, nb = b * rs;
    const long ia = (long)r * Dm + t, ib = ia + 256;
    h16 h;
    float v;
    v = na * w0[t];       h = f2h(v); y0[ia] = h; y0[ia + plane] = f2h(v - (float)h);
    v = nb * w0[t + 256]; h = f2h(v); y0[ib] = h; y0[ib + plane] = f2h(v - (float)h);
    v = na * w1[t];       h = f2h(v); y1[ia] = h; y1[ia + plane] = f2h(v - (float)h);
    v = nb * w1[t + 256]; h = f2h(v); y1[ib] = h; y1[ib + plane] = f2h(v - (float)h);
    v = na * w2[t];       h = f2h(v); y2[ia] = h; y2[ia + plane] = f2h(v - (float)h);
    v = nb * w2[t + 256]; h = f2h(v); y2[ib] = h; y2[ib + plane] = f2h(v - (float)h);
}

// =====================================================================
// GLU * exact GELU; h is [NT, 2816]-strided fp32; output fp16 hi/lo, KFF cols.
// =====================================================================
__global__ __launch_bounds__(256) void glu_gelu_bf(
    const float* __restrict__ h, h16* __restrict__ y, long plane)
{
    const int r = blockIdx.x;
    const float* row = h + (long)r * NFF;
    for (int c = threadIdx.x; c < KFF; c += 256) {
        float v = 0.f;
        if (c < DFF) {
            const float sim = row[c];
            const float g = row[c + DFF];
            v = sim * (0.5f * g * (1.f + erff(g * 0.70710678118654752440f)));
        }
        const long idx = (long)r * KFF + c;
        const h16 hi = f2h(v);
        y[idx] = hi;
        y[idx + plane] = f2h(v - (float)hi);
    }
}

// =====================================================================
// Self-attention: grid = BBAT*NH*4 (4 query-chunks of 64), block 256.
// 4 threads per query, each owning a 16-dim slice. Output: fp16 hi/lo.
// =====================================================================
__global__ __launch_bounds__(256) void attn_self_kernel(
    const float* __restrict__ qb, const float* __restrict__ kvb,
    h16* __restrict__ outbf, long plane)
{
    const int blk = blockIdx.x;
    const int qc = blk & 3;
    const int h = (blk >> 2) & 7;
    const int bat = blk >> 5;
    const int t = threadIdx.x;
    const int qi = t >> 2;
    const int ds = (t & 3) * 16;
    __shared__ float k_lds[64][DH];
    __shared__ float v_lds[64][DH];

    const long qrow = (long)(bat * Nn_ + qc * 64 + qi);
    const float* qp = qb + qrow * Dm + h * DH + ds;
    float q[16], o[16];
    #pragma unroll
    for (int d = 0; d < 16; d += 4) {
        const float4 v = *(const float4*)(qp + d);
        q[d] = v.x; q[d + 1] = v.y; q[d + 2] = v.z; q[d + 3] = v.w;
        o[d] = 0.f; o[d + 1] = 0.f; o[d + 2] = 0.f; o[d + 3] = 0.f;
    }
    float mx = -1e30f, l = 0.f;

    for (int jc = 0; jc < Nn_; jc += 64) {
        __syncthreads();
        {
            const int r = t >> 2;
            const int c = (t & 3) * 16;
            const float* kr = kvb + (long)(bat * Nn_ + jc + r) * 1024 + h * DH + c;
            #pragma unroll
            for (int cc = 0; cc < 16; cc += 4) {
                *(float4*)&k_lds[r][c + cc] = *(const float4*)(kr + cc);
                *(float4*)&v_lds[r][c + cc] = *(const float4*)(kr + 512 + cc);
            }
        }
        __syncthreads();
        for (int j = 0; j < 64; ++j) {
            float s = 0.f;
            #pragma unroll
            for (int d = 0; d < 16; ++d) s = fmaf(q[d], k_lds[j][ds + d], s);
            s += __shfl_xor(s, 1, 64);
            s += __shfl_xor(s, 2, 64);
            const float nm = fmaxf(mx, s);
            const float corr = __expf(mx - nm);
            const float p = __expf(s - nm);
            l = l * corr + p;
            #pragma unroll
            for (int d = 0; d < 16; ++d) o[d] = fmaf(p, v_lds[j][ds + d], o[d] * corr);
            mx = nm;
        }
    }
    const float inv = 1.f / l;
    const long obase = qrow * Dm + h * DH + ds;
    #pragma unroll
    for (int d = 0; d < 16; ++d) {
        const float v = o[d] * inv;
        const h16 hi = f2h(v);
        outbf[obase + d] = hi;
        outbf[obase + d + plane] = f2h(v - (float)hi);
    }
}

// =====================================================================
// Pooled attention, lane-per-m: block per (rb, head), 384 thr = 6 waves.
// =====================================================================
template <int M>
__global__ __launch_bounds__(384) void attn_pool_kernel(
    const float* __restrict__ qb, const float* __restrict__ kvc2,
    h16* __restrict__ outbf, long plane)
{
    const int rb = blockIdx.x >> 3;
    const int h = blockIdx.x & 7;
    __shared__ float k_lds[M * 66];
    __shared__ float v_lds[M * 66];
    __shared__ float q_lds[6 * 64];
    __shared__ float p_lds[6 * 64];
    const int t = threadIdx.x;
    const int cb = rb >> 8, nn = rb & 255;

    for (int idx = t; idx < M * 64; idx += 384) {
        const int m = idx >> 6, d = idx & 63;
        const long base = ((long)rb * MMAX + m) * 1024 + h * DH + d;
        k_lds[m * 66 + d] = kvc2[base];
        v_lds[m * 66 + d] = kvc2[base + 512];
    }
    {
        const int w = t >> 6, dd = t & 63;
        const long iq = (long)cb * 1536 + nn + w * 256;
        q_lds[t] = qb[iq * Dm + h * DH + dd];
    }
    __syncthreads();

    const int w = t >> 6;
    const int lane = t & 63;
    float s = -1e30f;
    if (lane < M) {
        s = 0.f;
        const float* kr = &k_lds[lane * 66];
        const float* qr = &q_lds[w * 64];
        #pragma unroll
        for (int dd = 0; dd < 64; dd += 2) {
            s = fmaf(qr[dd], kr[dd], s);
            s = fmaf(qr[dd + 1], kr[dd + 1], s);
        }
    }
    float mx = s;
    #pragma unroll
    for (int off = 32; off > 0; off >>= 1) mx = fmaxf(mx, __shfl_xor(mx, off, 64));
    const float p = __expf(s - mx);
    float l = p;
    #pragma unroll
    for (int off = 32; off > 0; off >>= 1) l += __shfl_xor(l, off, 64);
    p_lds[w * 64 + lane] = p / l;

    float o = 0.f;
    const float* pr = &p_lds[w * 64];
    #pragma unroll
    for (int m = 0; m < M; ++m)
        o = fmaf(pr[m], v_lds[m * 66 + lane], o);

    const long iq = (long)cb * 1536 + nn + w * 256;
    const long oidx = iq * Dm + h * DH + lane;
    const h16 hi = f2h(o);
    outbf[oidx] = hi;
    outbf[oidx + plane] = f2h(o - (float)hi);
}

// =====================================================================
// Broadcast tokens [2,256,512] -> tokens fp32, tokbf hi/lo, msgs set0
// =====================================================================
__global__ void replicate_kernel(const float* __restrict__ src,
                                 float* __restrict__ tokens,
                                 h16* __restrict__ tokbf, long tpl,
                                 h16* __restrict__ msg0, long mpl)
{
    const int idx = blockIdx.x * blockDim.x + threadIdx.x;
    if (idx >= NT * Dm) return;
    const float v = src[idx & (Bv * Nn_ * Dm - 1)];
    tokens[idx] = v;
    const h16 hi = f2h(v);
    const h16 lo = f2h(v - (float)hi);
    tokbf[idx] = hi; tokbf[idx + tpl] = lo;
    msg0[idx] = hi; msg0[idx + mpl] = lo;
}

// =====================================================================
extern "C" void kernel_launch(void* const* d_in, const int* in_sizes, int n_in,
                              void* d_out, int out_size, void* d_ws, size_t ws_size,
                              hipStream_t stream)
{
    const float* tok_in       = (const float*)d_in[0];
    const float* attn_norm_w  = (const float*)d_in[1];
    const float* attn_wq      = (const float*)d_in[2];
    const float* attn_wkv     = (const float*)d_in[3];
    const float* attn_wo      = (const float*)d_in[4];
    const float* ff_norm_w    = (const float*)d_in[5];
    const float* ff_keys_w    = (const float*)d_in[6];
    const float* ff_keys_b    = (const float*)d_in[7];
    const float* ff_values_w  = (const float*)d_in[8];
    const float* ff_values_b  = (const float*)d_in[9];
    const float* res_norm_w   = (const float*)d_in[10];
    const float* res_wq       = (const float*)d_in[11];
    const float* res_wkv      = (const float*)d_in[12];
    const float* res_wo       = (const float*)d_in[13];

    float* ws = (float*)d_ws;
    float* kvc2   = ws;                                  // 512*42*1024
    float* tokens = kvc2 + 512L * MMAX * 1024;           // NT*512
    float* qbuf   = tokens + (long)NT * Dm;              // NT*512
    float* kvbuf  = qbuf + (long)NT * Dm;                // NT*1024
    float* hbuf   = kvbuf + (long)NT * 1024;             // NT*2816

    h16* us = (h16*)(hbuf + (long)NT * NFF);
    const long apl = (long)NT * Dm;          // activation plane
    const long mpl = 7L * NT * Dm;           // msgs plane (7 sets)
    const long hpl = (long)NT * KFF;
    const long w1 = 512L * 512, w2 = 1024L * 512, w3 = (long)NFF * 512, w4 = 512L * KFF;
    h16* msgs_bf = us; us += 2 * mpl;
    h16* tokbf   = us; us += 2 * apl;
    h16* xa      = us; us += 2 * apl;
    h16* xf      = us; us += 2 * apl;
    h16* xr      = us; us += 2 * apl;
    h16* abf     = us; us += 2 * apl;
    h16* hbf     = us; us += 2 * hpl;
    h16* wqb  = us; us += 2 * w1;
    h16* wkvb = us; us += 2 * w2;
    h16* wob  = us; us += 2 * w1;
    h16* fkb  = us; us += 2 * w3;
    h16* fvb  = us; us += 2 * w4;
    h16* rqb  = us; us += 2 * w1;
    h16* rkvb = us; us += 2 * w2;
    h16* rob  = us; us += 2 * w1;

    auto cvtw = [&](const float* src, int Ms, int Ks, int Kp, int Mpad,
                    h16* dst, long pl) {
        const int tot = Mpad * Kp;
        cvt_hilo<<<(tot + 255) / 256, 256, 0, stream>>>(src, Ms, Ks, Kp, dst, pl, tot);
    };
    cvtw(attn_wq,     512,  512,  512, 512,  wqb,  w1);
    cvtw(attn_wkv,    1024, 512,  512, 1024, wkvb, w2);
    cvtw(attn_wo,     512,  512,  512, 512,  wob,  w1);
    cvtw(ff_keys_w,   DFF2, 512,  512, NFF,  fkb,  w3);
    cvtw(ff_values_w, 512,  DFF,  KFF, 512,  fvb,  w4);
    cvtw(res_wq,      512,  512,  512, 512,  rqb,  w1);
    cvtw(res_wkv,    1024,  512,  512, 1024, rkvb, w2);
    cvtw(res_wo,      512,  512,  512, 512,  rob,  w1);

    replicate_kernel<<<(NT * Dm + 255) / 256, 256, 0, stream>>>(
        tok_in, tokens, tokbf, apl, msgs_bf, mpl);

    auto mk = [](const h16* A, long Apl, int lda,
                 const h16* W, long Wpl, int ldw,
                 const float* bias, float* C, int ldc, int Nd,
                 h16* Cbf, long bfpl, int mbase, int K,
                 int mode, int nbx) -> GDesc {
        GDesc d;
        d.A = A; d.Apl = Apl; d.lda = lda;
        d.W = W; d.Wpl = Wpl; d.ldw = ldw;
        d.bias = bias; d.C = C; d.ldc = ldc; d.Nd = Nd;
        d.Cbf = Cbf; d.bfpl = bfpl; d.mbase = mbase; d.K = K;
        d.mode = mode; d.nbx = nbx;
        return d;
    };

    for (int e = 0; e < 3; ++e) {
        rmsnorm3_bf<<<NT, 256, 0, stream>>>(tokens, attn_norm_w, ff_norm_w, res_norm_w,
                                            xa, xf, xr, apl);
        // ---- B1: wq + wkv + ffk (816 blocks) ----
        {
            GDesc dwq  = mk(xa,    apl, 512, wqb,  w1, 512, nullptr,   qbuf,  512,  512,  nullptr, 0, 0, 512, 0, 24);
            GDesc dwkv = mk(tokbf, apl, 512, wkvb, w2, 512, nullptr,   kvbuf, 1024, 1024, nullptr, 0, 0, 512, 0, 24);
            GDesc dffk = mk(xf,    apl, 512, fkb,  w3, 512, ff_keys_b, hbuf,  NFF,  DFF2, nullptr, 0, 0, 512, 0, 24);
            mega_gemm<128><<<816, 256, 0, stream>>>(dwq, dwkv, dffk, 96, 288);
        }
        attn_self_kernel<<<BBAT * NH * 4, 256, 0, stream>>>(qbuf, kvbuf, abf, apl);
        glu_gelu_bf<<<NT, 256, 0, stream>>>(hbuf, hbf, hpl);
        // ---- B2: wo + ffv (384 blocks, BM=64) ----
        {
            GDesc dwo  = mk(abf, apl, 512,  wob, w1, 512,  nullptr,     nullptr, 512, 512,
                            msgs_bf + (1 + 2 * e) * (long)NT * Dm, mpl, 0, 512, 1, 48);
            GDesc dffv = mk(hbf, hpl, KFF,  fvb, w4, KFF,  ff_values_b, nullptr, 512, 512,
                            msgs_bf + (2 + 2 * e) * (long)NT * Dm, mpl, 0, KFF, 1, 48);
            mega_gemm<64><<<384, 256, 0, stream>>>(dwo, dffv, dffv, 192, 384);
        }
        // ---- B3: rkv (remap) + rq ----
        {
            const int s0 = (e == 0) ? 0 : (1 + 2 * e);
            const int ns = (e == 0) ? 3 : 2;
            GDesc drkv = mk(msgs_bf + (long)s0 * NT * Dm, mpl, 512, rkvb, w2, 512,
                            nullptr, kvc2, 1024, 1024, nullptr, 0, s0 * 6, 512, 3, ns * 24);
            GDesc drq  = mk(xr, apl, 512, rqb, w1, 512, nullptr, qbuf, 512, 512,
                            nullptr, 0, 0, 512, 0, 24);
            const int nrkv = ns * 24 * 8;
            mega_gemm<128><<<nrkv + 96, 256, 0, stream>>>(drkv, drq, drq, nrkv, nrkv + 96);
        }
        // ---- pooled attention ----
        if (e == 0)      attn_pool_kernel<18><<<512 * NH, 384, 0, stream>>>(qbuf, kvc2, abf, apl);
        else if (e == 1) attn_pool_kernel<30><<<512 * NH, 384, 0, stream>>>(qbuf, kvc2, abf, apl);
        else             attn_pool_kernel<42><<<512 * NH, 384, 0, stream>>>(qbuf, kvc2, abf, apl);
        // ---- B4: ro ----
        {
            if (e < 2) {
                GDesc dro = mk(abf, apl, 512, rob, w1, 512, nullptr, tokens, 512, 512,
                               tokbf, apl, 0, 512, 2, 48);
                mega_gemm<64><<<192, 256, 0, stream>>>(dro, dro, dro, 192, 192);
            } else {
                GDesc dro = mk(abf, apl, 512, rob, w1, 512, nullptr, (float*)d_out, 512, 512,
                               nullptr, 0, 0, 512, 0, 48);
                mega_gemm<64><<<192, 256, 0, stream>>>(dro, dro, dro, 192, 192);
            }
        }
    }
}

// Round 8
// 842.651 us; speedup vs baseline: 3.7977x; 1.1158x over previous
//
#include <hip/hip_runtime.h>
#include <math.h>

// ---- problem constants ----
#define Dm   512
#define Nn_  256
#define Bv   2
#define NBLK 6
#define BBAT 12            // NBLK*Bv
#define NT   3072          // BBAT*Nn_
#define NH   8
#define DH   64
#define DFF  1365
#define DFF2 2730
#define KFF  1408          // DFF padded to mult of 32 (ffv K)
#define NFF  2816          // DFF2 padded to mult of 128 (ffk N)
#define MMAX 42            // max pooled-context messages
#define EPSR 1.1920929e-07f

typedef _Float16 h16;
typedef h16  v8h  __attribute__((ext_vector_type(8)));
typedef float v4f __attribute__((ext_vector_type(4)));

__device__ inline h16 f2h(float v) { return (h16)v; }   // v_cvt_f16_f32, RNE

__device__ inline void glds16(const void* g, void* l) {
    __builtin_amdgcn_global_load_lds((const __attribute__((address_space(1))) void*)g,
                                     (__attribute__((address_space(3))) void*)l, 16, 0, 0);
}

// =====================================================================
// Multi-GEMM dispatcher, fp16 3-term compensated, double-buffered LDS.
//   A = Ah + Al (fp16 planes, lo at +Apl); W = Wh + Wl (lo at +Wpl).
//   acc += Ah*Wh + Ah*Wl + Al*Wh   (drops only Al*Wl ~ 2^-24 rel)
// modes: 0 fp32 C; 1 fp16 hi/lo Cbf; 2 both; 3 fp32 pooled-ctx remap;
//        4 attention KV split: col<512 -> Cbf (K, [row][512] hi/lo),
//          col>=512 -> (h16*)C as V^T [bat*8+head][dim][j] hi/lo.
// =====================================================================
struct GDesc {
    const h16* A;
    const h16* W;
    const float* bias;
    float* C;
    h16* Cbf;
    long Apl, Wpl, bfpl;
    int lda, ldw, ldc, Nd, mbase, K, mode, nbx;
};

template <int BM>
__global__ __launch_bounds__(256) void mega_gemm(GDesc d0, GDesc d1, GDesc d2,
                                                 int n0, int n01)
{
    constexpr int MI = BM / 32;
    constexpr int ASEG = BM / 16;
    constexpr int NSEG = 2 * ASEG + 16;
    constexpr int BUF = 2 * BM * 32 + 2 * 4096;
    constexpr int AH = 0, AL = BM * 32, WH = 2 * BM * 32, WL = 2 * BM * 32 + 4096;
    __shared__ h16 lds[2 * BUF];

    GDesc d; int lb = blockIdx.x;
    if (lb < n0) d = d0;
    else if (lb < n01) { d = d1; lb -= n0; }
    else { d = d2; lb -= n01; }
    const int bx = lb % d.nbx;
    const int by = lb / d.nbx;

    const int tid = threadIdx.x;
    const int wid = tid >> 6;
    const int lane = tid & 63;
    const int wm = wid >> 1, wn = wid & 1;
    const int row16 = lane & 15, quad = lane >> 4;
    const long i0 = (long)bx * BM;
    const long j0 = (long)by * 128;
    const int l4 = lane >> 2;
    const int l2s = ((lane & 3) ^ (l4 & 3)) * 8;
    const int ksw = (quad ^ (row16 & 3)) * 8;

    auto stage = [&](int k0, h16* buf) {
        #pragma unroll
        for (int s = 0; s < NSEG / 4; ++s) {
            const int sg = wid * (NSEG / 4) + s;
            const h16* src;
            int dst;
            if (sg < ASEG) {
                src = d.A + (i0 + sg * 16 + l4) * (long)d.lda + k0 + l2s;
                dst = AH + sg * 512;
            } else if (sg < 2 * ASEG) {
                const int r = sg - ASEG;
                src = d.A + d.Apl + (i0 + r * 16 + l4) * (long)d.lda + k0 + l2s;
                dst = AL + r * 512;
            } else if (sg < 2 * ASEG + 8) {
                const int r = sg - 2 * ASEG;
                src = d.W + (j0 + r * 16 + l4) * (long)d.ldw + k0 + l2s;
                dst = WH + r * 512;
            } else {
                const int r = sg - 2 * ASEG - 8;
                src = d.W + d.Wpl + (j0 + r * 16 + l4) * (long)d.ldw + k0 + l2s;
                dst = WL + r * 512;
            }
            glds16(src, &buf[dst]);
        }
    };

    v4f acc[MI][4];
    #pragma unroll
    for (int a = 0; a < MI; ++a)
        #pragma unroll
        for (int b = 0; b < 4; ++b) acc[a][b] = (v4f){0.f, 0.f, 0.f, 0.f};

    stage(0, lds);
    int cur = 0;
    for (int k0 = 0; k0 < d.K; k0 += 32) {
        __syncthreads();
        h16* cbuf = &lds[cur * BUF];
        if (k0 + 32 < d.K) stage(k0 + 32, &lds[(cur ^ 1) * BUF]);

        v8h af[MI], al[MI];
        #pragma unroll
        for (int mi = 0; mi < MI; ++mi) {
            const int aoff = (wm * (BM / 2) + mi * 16 + row16) * 32 + ksw;
            af[mi] = *(const v8h*)&cbuf[AH + aoff];
            al[mi] = *(const v8h*)&cbuf[AL + aoff];
        }
        #pragma unroll
        for (int nj = 0; nj < 4; ++nj) {
            const int boff = (wn * 64 + nj * 16 + row16) * 32 + ksw;
            v8h bh = *(const v8h*)&cbuf[WH + boff];
            v8h bl = *(const v8h*)&cbuf[WL + boff];
            #pragma unroll
            for (int mi = 0; mi < MI; ++mi) {
                acc[mi][nj] = __builtin_amdgcn_mfma_f32_16x16x32_f16(af[mi], bh, acc[mi][nj], 0, 0, 0);
                acc[mi][nj] = __builtin_amdgcn_mfma_f32_16x16x32_f16(af[mi], bl, acc[mi][nj], 0, 0, 0);
                acc[mi][nj] = __builtin_amdgcn_mfma_f32_16x16x32_f16(al[mi], bh, acc[mi][nj], 0, 0, 0);
            }
        }
        cur ^= 1;
    }

    #pragma unroll
    for (int nj = 0; nj < 4; ++nj) {
        const int col = (int)j0 + wn * 64 + nj * 16 + row16;
        if (col < d.Nd) {
            const float bv = d.bias ? d.bias[col] : 0.f;
            #pragma unroll
            for (int mi = 0; mi < MI; ++mi) {
                #pragma unroll
                for (int r = 0; r < 4; ++r) {
                    const long row = i0 + wm * (BM / 2) + mi * 16 + quad * 4 + r;
                    const float v = acc[mi][nj][r] + bv;
                    if (d.mode == 0) {
                        d.C[row * (long)d.ldc + col] = v;
                    } else if (d.mode == 1) {
                        const long idx = row * (long)d.ldc + col;
                        const h16 hi = f2h(v);
                        d.Cbf[idx] = hi; d.Cbf[idx + d.bfpl] = f2h(v - (float)hi);
                    } else if (d.mode == 2) {
                        const long idx = row * (long)d.ldc + col;
                        d.C[idx] = v;
                        const h16 hi = f2h(v);
                        d.Cbf[idx] = hi; d.Cbf[idx + d.bfpl] = f2h(v - (float)hi);
                    } else if (d.mode == 3) {
                        const int srel = (int)(row / 3072);
                        const int rr = (int)row - srel * 3072;
                        const long orow = (long)(rr & 511) * MMAX + d.mbase + srel * 6 + (rr >> 9);
                        d.C[orow * 1024 + col] = v;
                    } else {
                        const h16 hi = f2h(v);
                        const h16 lo = f2h(v - (float)hi);
                        if (col < 512) {
                            const long idx = row * 512 + col;
                            d.Cbf[idx] = hi; d.Cbf[idx + d.bfpl] = lo;
                        } else {
                            const int c = col - 512;
                            const int bh_ = ((int)(row >> 8)) * 8 + (c >> 6);
                            const long idx = (((long)bh_ * 64 + (c & 63)) << 8) + (row & 255);
                            h16* vtp = (h16*)d.C;
                            vtp[idx] = hi; vtp[idx + d.bfpl] = lo;
                        }
                    }
                }
            }
        }
    }
}

// =====================================================================
// fp32 -> fp16 hi/lo planes, with zero-padding
// =====================================================================
__global__ void cvt_hilo(const float* __restrict__ x, int Ms, int Ks, int Kp,
                         h16* __restrict__ y, long plane, int total)
{
    const int idx = blockIdx.x * 256 + threadIdx.x;
    if (idx >= total) return;
    const int row = idx / Kp;
    const int col = idx - row * Kp;
    const float v = (row < Ms && col < Ks) ? x[(long)row * Ks + col] : 0.f;
    const h16 hi = f2h(v);
    y[idx] = hi;
    y[idx + plane] = f2h(v - (float)hi);
}

// =====================================================================
// Triple RMSNorm: same row -> same rsqrt; writes 3 fp16 hi/lo outputs.
// =====================================================================
__global__ __launch_bounds__(256) void rmsnorm3_bf(
    const float* __restrict__ x,
    const float* __restrict__ w0, const float* __restrict__ w1,
    const float* __restrict__ w2,
    h16* __restrict__ y0, h16* __restrict__ y1,
    h16* __restrict__ y2, long plane)
{
    const int r = blockIdx.x;
    const float* xr = x + (long)r * Dm;
    const int t = threadIdx.x;
    const float a = xr[t];
    const float b = xr[t + 256];
    float ss = a * a + b * b;
    #pragma unroll
    for (int off = 32; off > 0; off >>= 1) ss += __shfl_xor(ss, off, 64);
    __shared__ float w4[4];
    if ((t & 63) == 0) w4[t >> 6] = ss;
    __syncthreads();
    const float rs = rsqrtf((w4[0] + w4[1] + w4[2] + w4[3]) * (1.f / 512.f) + EPSR);
    const float na = a * rs, nb = b * rs;
    const long ia = (long)r * Dm + t, ib = ia + 256;
    h16 h;
    float v;
    v = na * w0[t];       h = f2h(v); y0[ia] = h; y0[ia + plane] = f2h(v - (float)h);
    v = nb * w0[t + 256]; h = f2h(v); y0[ib] = h; y0[ib + plane] = f2h(v - (float)h);
    v = na * w1[t];       h = f2h(v); y1[ia] = h; y1[ia + plane] = f2h(v - (float)h);
    v = nb * w1[t + 256]; h = f2h(v); y1[ib] = h; y1[ib + plane] = f2h(v - (float)h);
    v = na * w2[t];       h = f2h(v); y2[ia] = h; y2[ia + plane] = f2h(v - (float)h);
    v = nb * w2[t + 256]; h = f2h(v); y2[ib] = h; y2[ib + plane] = f2h(v - (float)h);
}

// =====================================================================
// GLU * exact GELU; h is [NT, 2816]-strided fp32; output fp16 hi/lo, KFF cols.
// =====================================================================
__global__ __launch_bounds__(256) void glu_gelu_bf(
    const float* __restrict__ h, h16* __restrict__ y, long plane)
{
    const int r = blockIdx.x;
    const float* row = h + (long)r * NFF;
    for (int c = threadIdx.x; c < KFF; c += 256) {
        float v = 0.f;
        if (c < DFF) {
            const float sim = row[c];
            const float g = row[c + DFF];
            v = sim * (0.5f * g * (1.f + erff(g * 0.70710678118654752440f)));
        }
        const long idx = (long)r * KFF + c;
        const h16 hi = f2h(v);
        y[idx] = hi;
        y[idx + plane] = f2h(v - (float)hi);
    }
}

// =====================================================================
// MFMA flash self-attention. Grid = bat(12) x head(8) x qtile(4); 256 thr.
// Wave w owns 16 q rows. Per 64-key chunk: stage K [j][dim] and V^T
// [dim][j] hi/lo into XOR-swizzled LDS (chunk c stored at c^(row&7) ->
// b128 reads hit 2-way banks), QK^T 3-term MFMA, online softmax in
// C-layout regs (row = quad*4+r, col = tile*16+row16), P -> LDS
// (A-layout round-trip, hi/lo), PV 3-term MFMA. Output fp16 hi/lo.
// =====================================================================
__global__ __launch_bounds__(256) void attn_self_mfma(
    const h16* __restrict__ qhl, const h16* __restrict__ khl,
    const h16* __restrict__ vtb, long pl, h16* __restrict__ outbf)
{
    __shared__ h16 kh[4096], kl[4096], vh[4096], vl[4096];
    __shared__ h16 pH[4 * 1024], pL[4 * 1024];

    const int bat = blockIdx.x >> 5;
    const int head = (blockIdx.x >> 2) & 7;
    const int qc = blockIdx.x & 3;
    const int t = threadIdx.x;
    const int w = t >> 6, lane = t & 63;
    const int row16 = lane & 15, quad = lane >> 4;

    // Q fragments (regs): A[m=row16][k=quad*8+..], 2 k-steps, hi+lo
    v8h qh[2], ql[2];
    {
        const long qrow = (long)bat * 256 + qc * 64 + w * 16 + row16;
        const h16* qp = qhl + qrow * 512 + head * 64 + quad * 8;
        qh[0] = *(const v8h*)qp;        qh[1] = *(const v8h*)(qp + 32);
        ql[0] = *(const v8h*)(qp + pl); ql[1] = *(const v8h*)(qp + pl + 32);
    }

    v4f O[4];
    #pragma unroll
    for (int i = 0; i < 4; ++i) O[i] = (v4f){0.f, 0.f, 0.f, 0.f};
    float m[4] = {-1e30f, -1e30f, -1e30f, -1e30f};
    float l[4] = {0.f, 0.f, 0.f, 0.f};

    const int sj = t >> 3;        // staging row 0..31
    const int sc = t & 7;         // staging chunk
    const long kbase = ((long)bat * 256) * 512 + head * 64;
    const long vbase = ((long)(bat * 8 + head) * 64) << 8;

    for (int jc = 0; jc < 256; jc += 64) {
        __syncthreads();
        #pragma unroll
        for (int rep = 0; rep < 2; ++rep) {
            const int row = sj + rep * 32;
            const int dsw = row * 64 + ((sc ^ (row & 7)) * 8);
            const h16* ks = khl + kbase + (long)(jc + row) * 512 + sc * 8;
            const h16* vs = vtb + vbase + ((long)row << 8) + jc + sc * 8;
            *(v8h*)&kh[dsw] = *(const v8h*)ks;
            *(v8h*)&kl[dsw] = *(const v8h*)(ks + pl);
            *(v8h*)&vh[dsw] = *(const v8h*)vs;
            *(v8h*)&vl[dsw] = *(const v8h*)(vs + pl);
        }
        __syncthreads();

        // ---- S = Q K^T (16q x 64k per wave) ----
        v4f S[4];
        #pragma unroll
        for (int i = 0; i < 4; ++i) S[i] = (v4f){0.f, 0.f, 0.f, 0.f};
        #pragma unroll
        for (int kk = 0; kk < 2; ++kk) {
            #pragma unroll
            for (int tile = 0; tile < 4; ++tile) {
                const int off = (tile * 16 + row16) * 64 + (((kk * 4 + quad) ^ (row16 & 7)) * 8);
                v8h bh = *(const v8h*)&kh[off];
                v8h bl = *(const v8h*)&kl[off];
                S[tile] = __builtin_amdgcn_mfma_f32_16x16x32_f16(qh[kk], bh, S[tile], 0, 0, 0);
                S[tile] = __builtin_amdgcn_mfma_f32_16x16x32_f16(qh[kk], bl, S[tile], 0, 0, 0);
                S[tile] = __builtin_amdgcn_mfma_f32_16x16x32_f16(ql[kk], bh, S[tile], 0, 0, 0);
            }
        }

        // ---- online softmax (rows = quad*4+r, cols across row16 lanes) ----
        float mc[4], sums[4], alpha[4];
        #pragma unroll
        for (int r = 0; r < 4; ++r) {
            float v = fmaxf(fmaxf(S[0][r], S[1][r]), fmaxf(S[2][r], S[3][r]));
            v = fmaxf(v, __shfl_xor(v, 1, 64));
            v = fmaxf(v, __shfl_xor(v, 2, 64));
            v = fmaxf(v, __shfl_xor(v, 4, 64));
            v = fmaxf(v, __shfl_xor(v, 8, 64));
            mc[r] = v;
        }
        #pragma unroll
        for (int r = 0; r < 4; ++r) {
            const float mn = fmaxf(m[r], mc[r]);
            alpha[r] = __expf(m[r] - mn);
            m[r] = mn;
            sums[r] = 0.f;
        }
        #pragma unroll
        for (int tile = 0; tile < 4; ++tile) {
            #pragma unroll
            for (int r = 0; r < 4; ++r) {
                const float p = __expf(S[tile][r] - m[r]);
                S[tile][r] = p;
                sums[r] += p;
            }
        }
        #pragma unroll
        for (int r = 0; r < 4; ++r) {
            float v = sums[r];
            v += __shfl_xor(v, 1, 64);
            v += __shfl_xor(v, 2, 64);
            v += __shfl_xor(v, 4, 64);
            v += __shfl_xor(v, 8, 64);
            l[r] = l[r] * alpha[r] + v;
        }
        #pragma unroll
        for (int tile = 0; tile < 4; ++tile)
            #pragma unroll
            for (int r = 0; r < 4; ++r) O[tile][r] *= alpha[r];

        // ---- P -> LDS (A-layout, swizzled, wave-private) ----
        #pragma unroll
        for (int tile = 0; tile < 4; ++tile) {
            const int chunkcol = tile * 2 + (row16 >> 3);
            #pragma unroll
            for (int r = 0; r < 4; ++r) {
                const int prow = quad * 4 + r;
                const int addr = w * 1024 + prow * 64 +
                                 ((chunkcol ^ (prow & 7)) * 8) + (row16 & 7);
                const float p = S[tile][r];
                const h16 hi = f2h(p);
                pH[addr] = hi;
                pL[addr] = f2h(p - (float)hi);
            }
        }

        // ---- O += P V ----
        #pragma unroll
        for (int kk = 0; kk < 2; ++kk) {
            const int poff = w * 1024 + row16 * 64 + (((kk * 4 + quad) ^ (row16 & 7)) * 8);
            v8h pa = *(const v8h*)&pH[poff];
            v8h pb = *(const v8h*)&pL[poff];
            #pragma unroll
            for (int tile = 0; tile < 4; ++tile) {
                const int off = (tile * 16 + row16) * 64 + (((kk * 4 + quad) ^ (row16 & 7)) * 8);
                v8h vbh = *(const v8h*)&vh[off];
                v8h vbl = *(const v8h*)&vl[off];
                O[tile] = __builtin_amdgcn_mfma_f32_16x16x32_f16(pa, vbh, O[tile], 0, 0, 0);
                O[tile] = __builtin_amdgcn_mfma_f32_16x16x32_f16(pa, vbl, O[tile], 0, 0, 0);
                O[tile] = __builtin_amdgcn_mfma_f32_16x16x32_f16(pb, vbh, O[tile], 0, 0, 0);
            }
        }
    }

    // ---- epilogue: O/l -> fp16 hi/lo ----
    #pragma unroll
    for (int tile = 0; tile < 4; ++tile) {
        const int dim = tile * 16 + row16;
        #pragma unroll
        for (int r = 0; r < 4; ++r) {
            const long grow = (long)bat * 256 + qc * 64 + w * 16 + quad * 4 + r;
            const float v = O[tile][r] / l[r];
            const long idx = grow * 512 + head * 64 + dim;
            const h16 hi = f2h(v);
            outbf[idx] = hi;
            outbf[idx + pl] = f2h(v - (float)hi);
        }
    }
}

// =====================================================================
// Pooled attention, lane-per-m: block per (rb, head), 384 thr = 6 waves.
// =====================================================================
template <int M>
__global__ __launch_bounds__(384) void attn_pool_kernel(
    const float* __restrict__ qb, const float* __restrict__ kvc2,
    h16* __restrict__ outbf, long plane)
{
    const int rb = blockIdx.x >> 3;
    const int h = blockIdx.x & 7;
    __shared__ float k_lds[M * 66];
    __shared__ float v_lds[M * 66];
    __shared__ float q_lds[6 * 64];
    __shared__ float p_lds[6 * 64];
    const int t = threadIdx.x;
    const int cb = rb >> 8, nn = rb & 255;

    for (int idx = t; idx < M * 64; idx += 384) {
        const int m = idx >> 6, d = idx & 63;
        const long base = ((long)rb * MMAX + m) * 1024 + h * DH + d;
        k_lds[m * 66 + d] = kvc2[base];
        v_lds[m * 66 + d] = kvc2[base + 512];
    }
    {
        const int w = t >> 6, dd = t & 63;
        const long iq = (long)cb * 1536 + nn + w * 256;
        q_lds[t] = qb[iq * Dm + h * DH + dd];
    }
    __syncthreads();

    const int w = t >> 6;
    const int lane = t & 63;
    float s = -1e30f;
    if (lane < M) {
        s = 0.f;
        const float* kr = &k_lds[lane * 66];
        const float* qr = &q_lds[w * 64];
        #pragma unroll
        for (int dd = 0; dd < 64; dd += 2) {
            s = fmaf(qr[dd], kr[dd], s);
            s = fmaf(qr[dd + 1], kr[dd + 1], s);
        }
    }
    float mx = s;
    #pragma unroll
    for (int off = 32; off > 0; off >>= 1) mx = fmaxf(mx, __shfl_xor(mx, off, 64));
    const float p = __expf(s - mx);
    float l = p;
    #pragma unroll
    for (int off = 32; off > 0; off >>= 1) l += __shfl_xor(l, off, 64);
    p_lds[w * 64 + lane] = p / l;

    float o = 0.f;
    const float* pr = &p_lds[w * 64];
    #pragma unroll
    for (int m = 0; m < M; ++m)
        o = fmaf(pr[m], v_lds[m * 66 + lane], o);

    const long iq = (long)cb * 1536 + nn + w * 256;
    const long oidx = iq * Dm + h * DH + lane;
    const h16 hi = f2h(o);
    outbf[oidx] = hi;
    outbf[oidx + plane] = f2h(o - (float)hi);
}

// =====================================================================
// Broadcast tokens [2,256,512] -> tokens fp32, tokbf hi/lo, msgs set0
// =====================================================================
__global__ void replicate_kernel(const float* __restrict__ src,
                                 float* __restrict__ tokens,
                                 h16* __restrict__ tokbf, long tpl,
                                 h16* __restrict__ msg0, long mpl)
{
    const int idx = blockIdx.x * blockDim.x + threadIdx.x;
    if (idx >= NT * Dm) return;
    const float v = src[idx & (Bv * Nn_ * Dm - 1)];
    tokens[idx] = v;
    const h16 hi = f2h(v);
    const h16 lo = f2h(v - (float)hi);
    tokbf[idx] = hi; tokbf[idx + tpl] = lo;
    msg0[idx] = hi; msg0[idx + mpl] = lo;
}

// =====================================================================
extern "C" void kernel_launch(void* const* d_in, const int* in_sizes, int n_in,
                              void* d_out, int out_size, void* d_ws, size_t ws_size,
                              hipStream_t stream)
{
    const float* tok_in       = (const float*)d_in[0];
    const float* attn_norm_w  = (const float*)d_in[1];
    const float* attn_wq      = (const float*)d_in[2];
    const float* attn_wkv     = (const float*)d_in[3];
    const float* attn_wo      = (const float*)d_in[4];
    const float* ff_norm_w    = (const float*)d_in[5];
    const float* ff_keys_w    = (const float*)d_in[6];
    const float* ff_keys_b    = (const float*)d_in[7];
    const float* ff_values_w  = (const float*)d_in[8];
    const float* ff_values_b  = (const float*)d_in[9];
    const float* res_norm_w   = (const float*)d_in[10];
    const float* res_wq       = (const float*)d_in[11];
    const float* res_wkv      = (const float*)d_in[12];
    const float* res_wo       = (const float*)d_in[13];

    float* ws = (float*)d_ws;
    float* kvc2   = ws;                                  // 512*42*1024
    float* tokens = kvc2 + 512L * MMAX * 1024;           // NT*512
    float* qbuf   = tokens + (long)NT * Dm;              // NT*512 (pool q)
    float* hbuf   = qbuf + (long)NT * Dm;                // NT*2816

    h16* us = (h16*)(hbuf + (long)NT * NFF);
    const long apl = (long)NT * Dm;          // activation plane
    const long mpl = 7L * NT * Dm;           // msgs plane (7 sets)
    const long hpl = (long)NT * KFF;
    const long w1 = 512L * 512, w2 = 1024L * 512, w3 = (long)NFF * 512, w4 = 512L * KFF;
    h16* msgs_bf = us; us += 2 * mpl;
    h16* tokbf   = us; us += 2 * apl;
    h16* xa      = us; us += 2 * apl;
    h16* xf      = us; us += 2 * apl;
    h16* xr      = us; us += 2 * apl;
    h16* abf     = us; us += 2 * apl;
    h16* hbf     = us; us += 2 * hpl;
    h16* qhl     = us; us += 2 * apl;   // self-attn Q hi/lo
    h16* khl     = us; us += 2 * apl;   // self-attn K hi/lo
    h16* vtb     = us; us += 2 * apl;   // self-attn V^T hi/lo
    h16* wqb  = us; us += 2 * w1;
    h16* wkvb = us; us += 2 * w2;
    h16* wob  = us; us += 2 * w1;
    h16* fkb  = us; us += 2 * w3;
    h16* fvb  = us; us += 2 * w4;
    h16* rqb  = us; us += 2 * w1;
    h16* rkvb = us; us += 2 * w2;
    h16* rob  = us; us += 2 * w1;

    auto cvtw = [&](const float* src, int Ms, int Ks, int Kp, int Mpad,
                    h16* dst, long pl) {
        const int tot = Mpad * Kp;
        cvt_hilo<<<(tot + 255) / 256, 256, 0, stream>>>(src, Ms, Ks, Kp, dst, pl, tot);
    };
    cvtw(attn_wq,     512,  512,  512, 512,  wqb,  w1);
    cvtw(attn_wkv,    1024, 512,  512, 1024, wkvb, w2);
    cvtw(attn_wo,     512,  512,  512, 512,  wob,  w1);
    cvtw(ff_keys_w,   DFF2, 512,  512, NFF,  fkb,  w3);
    cvtw(ff_values_w, 512,  DFF,  KFF, 512,  fvb,  w4);
    cvtw(res_wq,      512,  512,  512, 512,  rqb,  w1);
    cvtw(res_wkv,    1024,  512,  512, 1024, rkvb, w2);
    cvtw(res_wo,      512,  512,  512, 512,  rob,  w1);

    replicate_kernel<<<(NT * Dm + 255) / 256, 256, 0, stream>>>(
        tok_in, tokens, tokbf, apl, msgs_bf, mpl);

    auto mk = [](const h16* A, long Apl, int lda,
                 const h16* W, long Wpl, int ldw,
                 const float* bias, float* C, int ldc, int Nd,
                 h16* Cbf, long bfpl, int mbase, int K,
                 int mode, int nbx) -> GDesc {
        GDesc d;
        d.A = A; d.Apl = Apl; d.lda = lda;
        d.W = W; d.Wpl = Wpl; d.ldw = ldw;
        d.bias = bias; d.C = C; d.ldc = ldc; d.Nd = Nd;
        d.Cbf = Cbf; d.bfpl = bfpl; d.mbase = mbase; d.K = K;
        d.mode = mode; d.nbx = nbx;
        return d;
    };

    for (int e = 0; e < 3; ++e) {
        rmsnorm3_bf<<<NT, 256, 0, stream>>>(tokens, attn_norm_w, ff_norm_w, res_norm_w,
                                            xa, xf, xr, apl);
        // ---- B1: wq (fp16 out) + wkv (K/V^T fp16 out) + ffk (816 blocks) ----
        {
            GDesc dwq  = mk(xa,    apl, 512, wqb,  w1, 512, nullptr,   nullptr, 512, 512,
                            qhl, apl, 0, 512, 1, 24);
            GDesc dwkv = mk(tokbf, apl, 512, wkvb, w2, 512, nullptr,   (float*)vtb, 1024, 1024,
                            khl, apl, 0, 512, 4, 24);
            GDesc dffk = mk(xf,    apl, 512, fkb,  w3, 512, ff_keys_b, hbuf,  NFF,  DFF2,
                            nullptr, 0, 0, 512, 0, 24);
            mega_gemm<128><<<816, 256, 0, stream>>>(dwq, dwkv, dffk, 96, 288);
        }
        attn_self_mfma<<<BBAT * NH * 4, 256, 0, stream>>>(qhl, khl, vtb, apl, abf);
        glu_gelu_bf<<<NT, 256, 0, stream>>>(hbuf, hbf, hpl);
        // ---- B2: wo + ffv (384 blocks, BM=64) ----
        {
            GDesc dwo  = mk(abf, apl, 512,  wob, w1, 512,  nullptr,     nullptr, 512, 512,
                            msgs_bf + (1 + 2 * e) * (long)NT * Dm, mpl, 0, 512, 1, 48);
            GDesc dffv = mk(hbf, hpl, KFF,  fvb, w4, KFF,  ff_values_b, nullptr, 512, 512,
                            msgs_bf + (2 + 2 * e) * (long)NT * Dm, mpl, 0, KFF, 1, 48);
            mega_gemm<64><<<384, 256, 0, stream>>>(dwo, dffv, dffv, 192, 384);
        }
        // ---- B3: rkv (remap) + rq ----
        {
            const int s0 = (e == 0) ? 0 : (1 + 2 * e);
            const int ns = (e == 0) ? 3 : 2;
            GDesc drkv = mk(msgs_bf + (long)s0 * NT * Dm, mpl, 512, rkvb, w2, 512,
                            nullptr, kvc2, 1024, 1024, nullptr, 0, s0 * 6, 512, 3, ns * 24);
            GDesc drq  = mk(xr, apl, 512, rqb, w1, 512, nullptr, qbuf, 512, 512,
                            nullptr, 0, 0, 512, 0, 24);
            const int nrkv = ns * 24 * 8;
            mega_gemm<128><<<nrkv + 96, 256, 0, stream>>>(drkv, drq, drq, nrkv, nrkv + 96);
        }
        // ---- pooled attention ----
        if (e == 0)      attn_pool_kernel<18><<<512 * NH, 384, 0, stream>>>(qbuf, kvc2, abf, apl);
        else if (e == 1) attn_pool_kernel<30><<<512 * NH, 384, 0, stream>>>(qbuf, kvc2, abf, apl);
        else             attn_pool_kernel<42><<<512 * NH, 384, 0, stream>>>(qbuf, kvc2, abf, apl);
        // ---- B4: ro ----
        {
            if (e < 2) {
                GDesc dro = mk(abf, apl, 512, rob, w1, 512, nullptr, tokens, 512, 512,
                               tokbf, apl, 0, 512, 2, 48);
                mega_gemm<64><<<192, 256, 0, stream>>>(dro, dro, dro, 192, 192);
            } else {
                GDesc dro = mk(abf, apl, 512, rob, w1, 512, nullptr, (float*)d_out, 512, 512,
                               nullptr, 0, 0, 512, 0, 48);
                mega_gemm<64><<<192, 256, 0, stream>>>(dro, dro, dro, 192, 192);
            }
        }
    }
}